// Round 6
// baseline (519.353 us; speedup 1.0000x reference)
//
#include <hip/hip_runtime.h>
#include <hip/hip_bf16.h>
#include <math.h>

typedef __hip_bfloat16 bf16;
typedef __attribute__((ext_vector_type(8))) short short8;
typedef __attribute__((ext_vector_type(4))) float floatx4;

#define B_   2
#define S_   2048
#define D_   1024
#define H_   16
#define DH_  64
#define BS_  4096   // B_*S_
#define D3_  3072   // 3*D_
#define DF_  4096   // 4*D_

__device__ __forceinline__ float tof(float v) { return v; }
__device__ __forceinline__ float tof(bf16 v) { return __bfloat162float(v); }
__device__ __forceinline__ void stf(float* p, size_t i, float v) { p[i] = v; }
__device__ __forceinline__ void stf(bf16* p, size_t i, float v) { p[i] = __float2bfloat16(v); }

// async global->LDS 16B copy: lane's data lands at readfirstlane(lds)+lane*16
__device__ __forceinline__ void gload_lds16(const bf16* g, bf16* l) {
  __builtin_amdgcn_global_load_lds(
      (const __attribute__((address_space(1))) unsigned int*)g,
      (__attribute__((address_space(3))) unsigned int*)l, 16, 0, 0);
}

// ---------------------------------------------------------------------------
// fp32 -> bf16 weight conversion (vectorized x4)
// ---------------------------------------------------------------------------
__global__ __launch_bounds__(256) void cvt_f32_bf16(
    const float* __restrict__ in, bf16* __restrict__ out, int n4) {
  int i = blockIdx.x * 256 + threadIdx.x;
  if (i >= n4) return;
  float4 v = ((const float4*)in)[i];
  bf16 o[4] = {__float2bfloat16(v.x), __float2bfloat16(v.y),
               __float2bfloat16(v.z), __float2bfloat16(v.w)};
  ((ulong1*)out)[i] = *(ulong1*)o;
}

// ---------------------------------------------------------------------------
// LayerNorm (optionally fused with residual add): one block per row of D_=1024
// ---------------------------------------------------------------------------
template <bool FUSE, typename TA, typename TS>
__global__ __launch_bounds__(256) void resid_ln_kernel(
    const TA* __restrict__ a, const TS* __restrict__ skip,
    const float* __restrict__ w, const float* __restrict__ bias,
    bf16* __restrict__ x2, bf16* __restrict__ hout, float st, float s1t) {
  const int row = blockIdx.x;
  const int tid = threadIdx.x;
  const int base = tid * 4;
  const size_t roff = (size_t)row * D_;

  float xv[4];
#pragma unroll
  for (int i = 0; i < 4; i++) {
    float v = tof(a[roff + base + i]);
    if (FUSE) v = st * v + s1t * tof(skip[roff + base + i]);
    xv[i] = v;
  }
  if (FUSE) {
#pragma unroll
    for (int i = 0; i < 4; i++) x2[roff + base + i] = __float2bfloat16(xv[i]);
  }

  float ls = 0.f, lq = 0.f;
#pragma unroll
  for (int i = 0; i < 4; i++) { ls += xv[i]; lq += xv[i] * xv[i]; }

  __shared__ float ssum[256];
  __shared__ float ssq[256];
  ssum[tid] = ls; ssq[tid] = lq;
  __syncthreads();
  for (int off = 128; off > 0; off >>= 1) {
    if (tid < off) { ssum[tid] += ssum[tid + off]; ssq[tid] += ssq[tid + off]; }
    __syncthreads();
  }
  const float mean = ssum[0] * (1.0f / D_);
  const float var  = ssq[0] * (1.0f / D_) - mean * mean;
  const float rstd = rsqrtf(var + 1e-5f);

#pragma unroll
  for (int i = 0; i < 4; i++) {
    float v = (xv[i] - mean) * rstd * w[base + i] + bias[base + i];
    hout[roff + base + i] = __float2bfloat16(v);
  }
}

// ---------------------------------------------------------------------------
// MFMA GEMM: C[M,N] = epilogue( A[M,K] @ Bw[N,K]^T ), both bf16.
// 128x128 tile, BK=32, 4 waves 2x2, each wave 4x4 frags of 16x16x32.
// Staging via async global_load_lds (width 16) — m97 pattern.
// ---------------------------------------------------------------------------
template <int EPI, typename TC>
__global__ __launch_bounds__(256) void gemm_mfma(
    const bf16* __restrict__ A, const bf16* __restrict__ Bw,
    TC* __restrict__ C, int M, int N, int K, float scale,
    const float* __restrict__ bias, const bf16* __restrict__ resid,
    float st, float s1t) {
  __shared__ __align__(16) bf16 As[128][32];
  __shared__ __align__(16) bf16 Bs[128][32];

  const int tid = threadIdx.x;
  const int lane = tid & 63;
  const int w = tid >> 6;
  const int wm = (w >> 1) * 64;
  const int wn = (w & 1) * 64;
  const int quad = lane >> 4;
  const int l16 = lane & 15;
  const int bm = blockIdx.y * 128, bn = blockIdx.x * 128;

  floatx4 acc[4][4];
#pragma unroll
  for (int i = 0; i < 4; i++)
#pragma unroll
    for (int j = 0; j < 4; j++) acc[i][j] = {0.f, 0.f, 0.f, 0.f};

  // chunk c (0..511) -> row c>>2, elem-offset (c&3)*8; LDS byte addr = c*16
  const int r0 = tid >> 2, o0 = (tid & 3) * 8;
  const int r1 = (tid + 256) >> 2, o1 = ((tid + 256) & 3) * 8;
  const bf16* Ap0 = A + (size_t)(bm + r0) * K + o0;
  const bf16* Ap1 = A + (size_t)(bm + r1) * K + o1;
  const bf16* Bp0 = Bw + (size_t)(bn + r0) * K + o0;
  const bf16* Bp1 = Bw + (size_t)(bn + r1) * K + o1;
  bf16* lAs0 = (bf16*)As + (size_t)tid * 8;
  bf16* lAs1 = (bf16*)As + (size_t)(tid + 256) * 8;
  bf16* lBs0 = (bf16*)Bs + (size_t)tid * 8;
  bf16* lBs1 = (bf16*)Bs + (size_t)(tid + 256) * 8;

  for (int k0 = 0; k0 < K; k0 += 32) {
    __syncthreads();
    gload_lds16(Ap0 + k0, lAs0);
    gload_lds16(Ap1 + k0, lAs1);
    gload_lds16(Bp0 + k0, lBs0);
    gload_lds16(Bp1 + k0, lBs1);
    __syncthreads();

    short8 af[4], bf[4];
#pragma unroll
    for (int f = 0; f < 4; f++) {
      af[f] = *(const short8*)&As[wm + f * 16 + l16][quad * 8];
      bf[f] = *(const short8*)&Bs[wn + f * 16 + l16][quad * 8];
    }
#pragma unroll
    for (int fi = 0; fi < 4; fi++)
#pragma unroll
      for (int fj = 0; fj < 4; fj++)
        acc[fi][fj] = __builtin_amdgcn_mfma_f32_16x16x32_bf16(
            af[fi], bf[fj], acc[fi][fj], 0, 0, 0);
  }

#pragma unroll
  for (int fi = 0; fi < 4; fi++) {
#pragma unroll
    for (int fj = 0; fj < 4; fj++) {
      const int col = bn + wn + fj * 16 + l16;
#pragma unroll
      for (int r = 0; r < 4; r++) {
        const int row = bm + wm + fi * 16 + quad * 4 + r;
        float v = acc[fi][fj][r];
        if (EPI == 0) {
          v *= scale;
        } else if (EPI == 1) {
          v = (v + bias[col]) * scale;
          v = 0.5f * v * (1.0f + erff(v * 0.70710678118654752f)) * st;
        } else {
          v = (v + bias[col]) * scale;
          v = st * v + s1t * __bfloat162float(resid[(size_t)row * N + col]);
        }
        stf(C, (size_t)row * N + col, v);
      }
    }
  }
}

// ---------------------------------------------------------------------------
// De-interleave qkv: qkv[b,s, d*48 + z*16 + h] -> QKV[z][b][h][s][d]
// ---------------------------------------------------------------------------
__global__ __launch_bounds__(256) void extract_qkv(
    const bf16* __restrict__ qkv, bf16* __restrict__ QKV) {
  size_t i = (size_t)blockIdx.x * 256 + threadIdx.x;
  const int d = (int)(i & 63);
  size_t r = i >> 6;
  const int ss = (int)(r & (S_ - 1)); r >>= 11;
  const int hh = (int)(r & (H_ - 1)); r >>= 4;
  const int bb = (int)(r & 1);
  const int z  = (int)(r >> 1);
  const int row = bb * S_ + ss;
  const int col = d * 48 + z * 16 + hh;
  QKV[i] = qkv[(size_t)row * D3_ + col];
}

// ---------------------------------------------------------------------------
// MFMA flash attention. Block = (64 Q-rows, head h, batch b), 256 thr / 4 waves.
// ---------------------------------------------------------------------------
__global__ __launch_bounds__(256) void flash_attn_mfma(
    const bf16* __restrict__ Q, const bf16* __restrict__ K,
    const bf16* __restrict__ V, bf16* __restrict__ att,
    float mm_scale, float out_scale) {
  const int qb = blockIdx.x * 64;
  const int h = blockIdx.y, b = blockIdx.z;
  const int bh = b * H_ + h;
  const int tid = threadIdx.x;
  const int lane = tid & 63;
  const int wv = tid >> 6;
  const int quad = lane >> 4;
  const int l16 = lane & 15;

  __shared__ __align__(16) bf16 Ks[64][72];
  __shared__ __align__(16) bf16 Vt[64][72];   // Vt[d][j] = V[j][d]
  __shared__ __align__(16) bf16 Ps[64][72];   // P natural [m][j], wave-private rows

  const bf16* Qb_ = Q + (size_t)bh * S_ * DH_;
  const bf16* Kb_ = K + (size_t)bh * S_ * DH_;
  const bf16* Vb_ = V + (size_t)bh * S_ * DH_;

  short8 aq0, aq1;
  {
    const bf16* qrow = Qb_ + (size_t)(qb + wv * 16 + l16) * DH_ + quad * 8;
    aq0 = *(const short8*)(qrow);
    aq1 = *(const short8*)(qrow + 32);
  }

  float m_r[4], l_r[4];
#pragma unroll
  for (int r = 0; r < 4; r++) { m_r[r] = -1e30f; l_r[r] = 0.f; }
  floatx4 o[4];
#pragma unroll
  for (int fd = 0; fd < 4; fd++) o[fd] = {0.f, 0.f, 0.f, 0.f};

  const int kr0 = tid >> 3, ko0 = (tid & 7) * 8;
  const int kr1 = (tid + 256) >> 3, ko1 = (tid & 7) * 8;
  const int vj0 = tid & 63, vd0 = (tid >> 6) * 8;
  const int vj1 = tid & 63, vd1 = ((tid + 256) >> 6) * 8;

  for (int t = 0; t < S_ / 64; t++) {
    __syncthreads();
    *(uint4*)&Ks[kr0][ko0] = *(const uint4*)(Kb_ + (size_t)(t * 64 + kr0) * DH_ + ko0);
    *(uint4*)&Ks[kr1][ko1] = *(const uint4*)(Kb_ + (size_t)(t * 64 + kr1) * DH_ + ko1);
    {
      bf16 tmp[8];
      *(uint4*)tmp = *(const uint4*)(Vb_ + (size_t)(t * 64 + vj0) * DH_ + vd0);
#pragma unroll
      for (int e = 0; e < 8; e++) Vt[vd0 + e][vj0] = tmp[e];
      *(uint4*)tmp = *(const uint4*)(Vb_ + (size_t)(t * 64 + vj1) * DH_ + vd1);
#pragma unroll
      for (int e = 0; e < 8; e++) Vt[vd1 + e][vj1] = tmp[e];
    }
    __syncthreads();

    float s[4][4];
#pragma unroll
    for (int fj = 0; fj < 4; fj++) {
      short8 bk0 = *(const short8*)&Ks[fj * 16 + l16][quad * 8];
      short8 bk1 = *(const short8*)&Ks[fj * 16 + l16][32 + quad * 8];
      floatx4 acc = {0.f, 0.f, 0.f, 0.f};
      acc = __builtin_amdgcn_mfma_f32_16x16x32_bf16(aq0, bk0, acc, 0, 0, 0);
      acc = __builtin_amdgcn_mfma_f32_16x16x32_bf16(aq1, bk1, acc, 0, 0, 0);
#pragma unroll
      for (int r = 0; r < 4; r++) s[fj][r] = acc[r] * mm_scale;
    }

#pragma unroll
    for (int r = 0; r < 4; r++) {
      float mx = fmaxf(fmaxf(s[0][r], s[1][r]), fmaxf(s[2][r], s[3][r]));
      mx = fmaxf(mx, __shfl_xor(mx, 1));
      mx = fmaxf(mx, __shfl_xor(mx, 2));
      mx = fmaxf(mx, __shfl_xor(mx, 4));
      mx = fmaxf(mx, __shfl_xor(mx, 8));
      const float mo = m_r[r];
      const float mn = fmaxf(mo, mx);
      m_r[r] = mn;
      const float alpha = __expf(mo - mn);
      float rs = 0.f;
#pragma unroll
      for (int fj = 0; fj < 4; fj++) {
        const float p = __expf(s[fj][r] - mn);
        rs += p;
        Ps[wv * 16 + quad * 4 + r][fj * 16 + l16] = __float2bfloat16(p);
      }
      rs += __shfl_xor(rs, 1);
      rs += __shfl_xor(rs, 2);
      rs += __shfl_xor(rs, 4);
      rs += __shfl_xor(rs, 8);
      l_r[r] = alpha * l_r[r] + rs;
#pragma unroll
      for (int fd = 0; fd < 4; fd++) o[fd][r] *= alpha;
    }

    short8 ap0 = *(const short8*)&Ps[wv * 16 + l16][quad * 8];
    short8 ap1 = *(const short8*)&Ps[wv * 16 + l16][32 + quad * 8];
#pragma unroll
    for (int fd = 0; fd < 4; fd++) {
      short8 bv0 = *(const short8*)&Vt[fd * 16 + l16][quad * 8];
      short8 bv1 = *(const short8*)&Vt[fd * 16 + l16][32 + quad * 8];
      o[fd] = __builtin_amdgcn_mfma_f32_16x16x32_bf16(ap0, bv0, o[fd], 0, 0, 0);
      o[fd] = __builtin_amdgcn_mfma_f32_16x16x32_bf16(ap1, bv1, o[fd], 0, 0, 0);
    }
  }

#pragma unroll
  for (int r = 0; r < 4; r++) {
    const float sc = out_scale / l_r[r];
    const size_t base =
        ((size_t)(b * S_ + qb + wv * 16 + quad * 4 + r)) * D_ + h * DH_;
#pragma unroll
    for (int fd = 0; fd < 4; fd++)
      att[base + fd * 16 + l16] = __float2bfloat16(o[fd][r] * sc);
  }
}

// ---------------------------------------------------------------------------
extern "C" void kernel_launch(void* const* d_in, const int* in_sizes, int n_in,
                              void* d_out, int out_size, void* d_ws, size_t ws_size,
                              hipStream_t stream) {
  const float* x     = (const float*)d_in[0];
  const float* w_qkv = (const float*)d_in[1];
  const float* w_o   = (const float*)d_in[2];
  const float* w1    = (const float*)d_in[3];
  const float* b1    = (const float*)d_in[4];
  const float* w2    = (const float*)d_in[5];
  const float* b2    = (const float*)d_in[6];
  const float* ln1w  = (const float*)d_in[7];
  const float* ln1b  = (const float*)d_in[8];
  const float* ln2w  = (const float*)d_in[9];
  const float* ln2b  = (const float*)d_in[10];
  float* out = (float*)d_out;
  bf16* ws  = (bf16*)d_ws;

  // workspace layout (bf16 elements), with reuse (peak 29,360,128 els = 58.7 MB)
  bf16* h1       = ws;                 // LN1 out; dead after QKV gemm
  bf16* Qb       = ws + 4194304;
  bf16* Kb       = ws + 8388608;
  bf16* Vb       = ws + 12582912;      // Q/K/V dead after flash
  bf16* qkv      = ws + 16777216;      // dead after extract
  bf16* att      = ws;                 // = h1 region
  bf16* attn_out = ws + 16777216;      // dead after LN2
  bf16* x2       = ws + 20971520;
  bf16* h2       = ws + 25165824;
  bf16* g        = ws;                 // h1+Q/K/V regions (dead)
  bf16* wqb      = ws + 4194304;       // overwritten by extract (ok)
  bf16* wob      = ws + 4194304;       // Q region, dead after flash
  bf16* w1b      = ws + 16777216;      // attn_out region, dead
  bf16* w2b      = ws + 16777216;      // w1b dead after FFN1

  const float MM_SCALE   = (float)pow((double)S_ * S_ * DH_, -1.0 / 6.0);
  const float SM_SCALE   = (float)((double)S_ / sqrt(1.31 * 1.65));
  const float GELU_SCALE = (float)pow(0.588 * 0.675, -0.5);
  const float SQRT_TAU   = (float)sqrt(0.2);
  const float SQRT_1MT   = (float)sqrt(0.8);
  const float qkv_scale  = (float)pow((double)D_ * D3_, -0.25);
  const float o_scale    = (float)pow((double)D_ * D_, -0.25);
  const float w1_scale   = (float)pow((double)D_ * DF_, -0.25);
  const float w2_scale   = (float)pow((double)DF_ * D_, -0.25);

  // 1. LN1
  resid_ln_kernel<false, float, float><<<BS_, 256, 0, stream>>>(
      x, nullptr, ln1w, ln1b, nullptr, h1, 0.f, 0.f);
  // 2. convert w_qkv; QKV gemm
  cvt_f32_bf16<<<(D3_ * D_ / 4 + 255) / 256, 256, 0, stream>>>(w_qkv, wqb, D3_ * D_ / 4);
  gemm_mfma<0, bf16><<<dim3(D3_ / 128, BS_ / 128), 256, 0, stream>>>(
      h1, wqb, qkv, BS_, D3_, D_, qkv_scale, nullptr, nullptr, 0.f, 0.f);
  // 3. de-interleave
  extract_qkv<<<(3 * BS_ * D_) / 256, 256, 0, stream>>>(qkv, Qb);
  // 4. MFMA flash attention
  flash_attn_mfma<<<dim3(S_ / 64, H_, B_), 256, 0, stream>>>(
      Qb, Kb, Vb, att, MM_SCALE, SM_SCALE * MM_SCALE);
  // 5. convert w_o; out-proj
  cvt_f32_bf16<<<(D_ * D_ / 4 + 255) / 256, 256, 0, stream>>>(w_o, wob, D_ * D_ / 4);
  gemm_mfma<0, bf16><<<dim3(D_ / 128, BS_ / 128), 256, 0, stream>>>(
      att, wob, attn_out, BS_, D_, D_, o_scale, nullptr, nullptr, 0.f, 0.f);
  // 6. residual + LN2
  resid_ln_kernel<true, bf16, float><<<BS_, 256, 0, stream>>>(
      attn_out, x, ln2w, ln2b, x2, h2, SQRT_TAU, SQRT_1MT);
  // 7. convert w1; FFN1 + GELU
  cvt_f32_bf16<<<(DF_ * D_ / 4 + 255) / 256, 256, 0, stream>>>(w1, w1b, DF_ * D_ / 4);
  gemm_mfma<1, bf16><<<dim3(DF_ / 128, BS_ / 128), 256, 0, stream>>>(
      h2, w1b, g, BS_, DF_, D_, w1_scale, b1, nullptr, GELU_SCALE, 0.f);
  // 8. convert w2; FFN2 + bias + final residual -> d_out (fp32)
  cvt_f32_bf16<<<(D_ * DF_ / 4 + 255) / 256, 256, 0, stream>>>(w2, w2b, D_ * DF_ / 4);
  gemm_mfma<2, float><<<dim3(D_ / 128, BS_ / 128), 256, 0, stream>>>(
      g, w2b, out, BS_, D_, DF_, w2_scale, b2, x2, SQRT_TAU, SQRT_1MT);
}

// Round 7
// 498.567 us; speedup vs baseline: 1.0417x; 1.0417x over previous
//
#include <hip/hip_runtime.h>
#include <hip/hip_bf16.h>
#include <math.h>

typedef __hip_bfloat16 bf16;
typedef __attribute__((ext_vector_type(8))) short short8;
typedef __attribute__((ext_vector_type(4))) float floatx4;

#define B_   2
#define S_   2048
#define D_   1024
#define H_   16
#define DH_  64
#define BS_  4096   // B_*S_
#define D3_  3072   // 3*D_
#define DF_  4096   // 4*D_

__device__ __forceinline__ float tof(float v) { return v; }
__device__ __forceinline__ float tof(bf16 v) { return __bfloat162float(v); }
__device__ __forceinline__ void stf(float* p, size_t i, float v) { p[i] = v; }
__device__ __forceinline__ void stf(bf16* p, size_t i, float v) { p[i] = __float2bfloat16(v); }

// async global->LDS 16B copy: lane's data lands at readfirstlane(lds)+lane*16
__device__ __forceinline__ void gload_lds16(const bf16* g, bf16* l) {
  __builtin_amdgcn_global_load_lds(
      (const __attribute__((address_space(1))) unsigned int*)g,
      (__attribute__((address_space(3))) unsigned int*)l, 16, 0, 0);
}

// ---------------------------------------------------------------------------
// fp32 -> bf16 weight conversion (vectorized x4)
// ---------------------------------------------------------------------------
__global__ __launch_bounds__(256) void cvt_f32_bf16(
    const float* __restrict__ in, bf16* __restrict__ out, int n4) {
  int i = blockIdx.x * 256 + threadIdx.x;
  if (i >= n4) return;
  float4 v = ((const float4*)in)[i];
  bf16 o[4] = {__float2bfloat16(v.x), __float2bfloat16(v.y),
               __float2bfloat16(v.z), __float2bfloat16(v.w)};
  ((ulong1*)out)[i] = *(ulong1*)o;
}

// ---------------------------------------------------------------------------
// LayerNorm (optionally fused with residual add): one block per row of D_=1024
// ---------------------------------------------------------------------------
template <bool FUSE, typename TA, typename TS>
__global__ __launch_bounds__(256) void resid_ln_kernel(
    const TA* __restrict__ a, const TS* __restrict__ skip,
    const float* __restrict__ w, const float* __restrict__ bias,
    bf16* __restrict__ x2, bf16* __restrict__ hout, float st, float s1t) {
  const int row = blockIdx.x;
  const int tid = threadIdx.x;
  const int base = tid * 4;
  const size_t roff = (size_t)row * D_;

  float xv[4];
#pragma unroll
  for (int i = 0; i < 4; i++) {
    float v = tof(a[roff + base + i]);
    if (FUSE) v = st * v + s1t * tof(skip[roff + base + i]);
    xv[i] = v;
  }
  if (FUSE) {
#pragma unroll
    for (int i = 0; i < 4; i++) x2[roff + base + i] = __float2bfloat16(xv[i]);
  }

  float ls = 0.f, lq = 0.f;
#pragma unroll
  for (int i = 0; i < 4; i++) { ls += xv[i]; lq += xv[i] * xv[i]; }

  __shared__ float ssum[256];
  __shared__ float ssq[256];
  ssum[tid] = ls; ssq[tid] = lq;
  __syncthreads();
  for (int off = 128; off > 0; off >>= 1) {
    if (tid < off) { ssum[tid] += ssum[tid + off]; ssq[tid] += ssq[tid + off]; }
    __syncthreads();
  }
  const float mean = ssum[0] * (1.0f / D_);
  const float var  = ssq[0] * (1.0f / D_) - mean * mean;
  const float rstd = rsqrtf(var + 1e-5f);

#pragma unroll
  for (int i = 0; i < 4; i++) {
    float v = (xv[i] - mean) * rstd * w[base + i] + bias[base + i];
    hout[roff + base + i] = __float2bfloat16(v);
  }
}

// ---------------------------------------------------------------------------
// MFMA GEMM: C[M,N] = epilogue( A[M,K] @ Bw[N,K]^T ), both bf16.
// BM x BN tile, BK=32, 4 waves 2x2; wave = (BM/2)x(BN/2), frags of 16x16x32.
// BM=BN=128 for big-N GEMMs; BM=64,BN=128 for N=1024 GEMMs (2 blocks/CU).
// ---------------------------------------------------------------------------
template <int EPI, int BM, int BN, typename TC>
__global__ __launch_bounds__(256) void gemm_mfma(
    const bf16* __restrict__ A, const bf16* __restrict__ Bw,
    TC* __restrict__ C, int M, int N, int K, float scale,
    const float* __restrict__ bias, const bf16* __restrict__ resid,
    float st, float s1t) {
  constexpr int FI = BM / 32;       // frags per wave (M)
  constexpr int FJ = BN / 32;       // frags per wave (N)
  constexpr int NA = BM * 4 / 256;  // 16B chunks per thread for A-tile
  constexpr int NB = BN * 4 / 256;

  __shared__ __align__(16) bf16 As[BM][32];
  __shared__ __align__(16) bf16 Bs[BN][32];

  const int tid = threadIdx.x;
  const int lane = tid & 63;
  const int w = tid >> 6;
  const int wm = (w >> 1) * (BM / 2);
  const int wn = (w & 1) * (BN / 2);
  const int quad = lane >> 4;
  const int l16 = lane & 15;
  const int bm = blockIdx.y * BM, bn = blockIdx.x * BN;

  floatx4 acc[FI][FJ];
#pragma unroll
  for (int i = 0; i < FI; i++)
#pragma unroll
    for (int j = 0; j < FJ; j++) acc[i][j] = {0.f, 0.f, 0.f, 0.f};

  const bf16* Ap[NA];
  bf16* lA[NA];
#pragma unroll
  for (int i = 0; i < NA; i++) {
    const int c = tid + i * 256;
    Ap[i] = A + (size_t)(bm + (c >> 2)) * K + (c & 3) * 8;
    lA[i] = (bf16*)As + (size_t)c * 8;
  }
  const bf16* Bp[NB];
  bf16* lB[NB];
#pragma unroll
  for (int i = 0; i < NB; i++) {
    const int c = tid + i * 256;
    Bp[i] = Bw + (size_t)(bn + (c >> 2)) * K + (c & 3) * 8;
    lB[i] = (bf16*)Bs + (size_t)c * 8;
  }

  for (int k0 = 0; k0 < K; k0 += 32) {
    __syncthreads();
#pragma unroll
    for (int i = 0; i < NA; i++) gload_lds16(Ap[i] + k0, lA[i]);
#pragma unroll
    for (int i = 0; i < NB; i++) gload_lds16(Bp[i] + k0, lB[i]);
    __syncthreads();

    short8 af[FI], bf[FJ];
#pragma unroll
    for (int f = 0; f < FI; f++)
      af[f] = *(const short8*)&As[wm + f * 16 + l16][quad * 8];
#pragma unroll
    for (int f = 0; f < FJ; f++)
      bf[f] = *(const short8*)&Bs[wn + f * 16 + l16][quad * 8];
#pragma unroll
    for (int fi = 0; fi < FI; fi++)
#pragma unroll
      for (int fj = 0; fj < FJ; fj++)
        acc[fi][fj] = __builtin_amdgcn_mfma_f32_16x16x32_bf16(
            af[fi], bf[fj], acc[fi][fj], 0, 0, 0);
  }

#pragma unroll
  for (int fi = 0; fi < FI; fi++) {
#pragma unroll
    for (int fj = 0; fj < FJ; fj++) {
      const int col = bn + wn + fj * 16 + l16;
#pragma unroll
      for (int r = 0; r < 4; r++) {
        const int row = bm + wm + fi * 16 + quad * 4 + r;
        float v = acc[fi][fj][r];
        if (EPI == 0) {
          v *= scale;
        } else if (EPI == 1) {
          v = (v + bias[col]) * scale;
          v = 0.5f * v * (1.0f + erff(v * 0.70710678118654752f)) * st;
        } else {
          v = (v + bias[col]) * scale;
          v = st * v + s1t * __bfloat162float(resid[(size_t)row * N + col]);
        }
        stf(C, (size_t)row * N + col, v);
      }
    }
  }
}

// ---------------------------------------------------------------------------
// De-interleave qkv: qkv[b,s, d*48 + z*16 + h] -> QKV[z][b][h][s][d]
// ---------------------------------------------------------------------------
__global__ __launch_bounds__(256) void extract_qkv(
    const bf16* __restrict__ qkv, bf16* __restrict__ QKV) {
  size_t i = (size_t)blockIdx.x * 256 + threadIdx.x;
  const int d = (int)(i & 63);
  size_t r = i >> 6;
  const int ss = (int)(r & (S_ - 1)); r >>= 11;
  const int hh = (int)(r & (H_ - 1)); r >>= 4;
  const int bb = (int)(r & 1);
  const int z  = (int)(r >> 1);
  const int row = bb * S_ + ss;
  const int col = d * 48 + z * 16 + hh;
  QKV[i] = qkv[(size_t)row * D3_ + col];
}

// ---------------------------------------------------------------------------
// MFMA flash attention. Block = (128 Q-rows, head h, batch b), 4 waves.
// Wave wv owns rows [wv*32, wv*32+32) as 2 fragments of 16.
// Ps stride 68: 4-row quad offset = 136 dw = 8 (mod 32) -> quads hit
// disjoint bank octets on P-writes (kills the round-5 4-way conflicts).
// ---------------------------------------------------------------------------
__global__ __launch_bounds__(256) void flash_attn_mfma(
    const bf16* __restrict__ Q, const bf16* __restrict__ K,
    const bf16* __restrict__ V, bf16* __restrict__ att,
    float mm_scale, float out_scale) {
  const int qb = blockIdx.x * 128;
  const int h = blockIdx.y, b = blockIdx.z;
  const int bh = b * H_ + h;
  const int tid = threadIdx.x;
  const int lane = tid & 63;
  const int wv = tid >> 6;
  const int quad = lane >> 4;
  const int l16 = lane & 15;

  __shared__ __align__(16) bf16 Ks[64][72];
  __shared__ __align__(16) bf16 Vt[64][72];   // Vt[d][j] = V[j][d]
  __shared__ __align__(16) bf16 Ps[128][68];  // P natural [m][j], wave-private rows

  const bf16* Qb_ = Q + (size_t)bh * S_ * DH_;
  const bf16* Kb_ = K + (size_t)bh * S_ * DH_;
  const bf16* Vb_ = V + (size_t)bh * S_ * DH_;

  // Q fragments: frag f covers rows qb + wv*32 + f*16 + l16
  short8 aq[2][2];
#pragma unroll
  for (int f = 0; f < 2; f++) {
    const bf16* qrow = Qb_ + (size_t)(qb + wv * 32 + f * 16 + l16) * DH_ + quad * 8;
    aq[f][0] = *(const short8*)(qrow);
    aq[f][1] = *(const short8*)(qrow + 32);
  }

  float m_r[2][4], l_r[2][4];
#pragma unroll
  for (int f = 0; f < 2; f++)
#pragma unroll
    for (int r = 0; r < 4; r++) { m_r[f][r] = -1e30f; l_r[f][r] = 0.f; }
  floatx4 o[2][4];
#pragma unroll
  for (int f = 0; f < 2; f++)
#pragma unroll
    for (int fd = 0; fd < 4; fd++) o[f][fd] = {0.f, 0.f, 0.f, 0.f};

  const int kr0 = tid >> 3, ko0 = (tid & 7) * 8;
  const int kr1 = (tid + 256) >> 3;
  const int vj0 = tid & 63, vd0 = (tid >> 6) * 8;
  const int vd1 = ((tid + 256) >> 6) * 8;

  for (int t = 0; t < S_ / 64; t++) {
    __syncthreads();
    *(uint4*)&Ks[kr0][ko0] = *(const uint4*)(Kb_ + (size_t)(t * 64 + kr0) * DH_ + ko0);
    *(uint4*)&Ks[kr1][ko0] = *(const uint4*)(Kb_ + (size_t)(t * 64 + kr1) * DH_ + ko0);
    {
      bf16 tmp[8];
      *(uint4*)tmp = *(const uint4*)(Vb_ + (size_t)(t * 64 + vj0) * DH_ + vd0);
#pragma unroll
      for (int e = 0; e < 8; e++) Vt[vd0 + e][vj0] = tmp[e];
      *(uint4*)tmp = *(const uint4*)(Vb_ + (size_t)(t * 64 + vj0) * DH_ + vd1);
#pragma unroll
      for (int e = 0; e < 8; e++) Vt[vd1 + e][vj0] = tmp[e];
    }
    __syncthreads();

    // S = Q K^T : 2 row-frags x 4 key-frags; bk loaded once per fj
    float s[2][4][4];
#pragma unroll
    for (int fj = 0; fj < 4; fj++) {
      short8 bk0 = *(const short8*)&Ks[fj * 16 + l16][quad * 8];
      short8 bk1 = *(const short8*)&Ks[fj * 16 + l16][32 + quad * 8];
#pragma unroll
      for (int f = 0; f < 2; f++) {
        floatx4 acc = {0.f, 0.f, 0.f, 0.f};
        acc = __builtin_amdgcn_mfma_f32_16x16x32_bf16(aq[f][0], bk0, acc, 0, 0, 0);
        acc = __builtin_amdgcn_mfma_f32_16x16x32_bf16(aq[f][1], bk1, acc, 0, 0, 0);
#pragma unroll
        for (int r = 0; r < 4; r++) s[f][fj][r] = acc[r] * mm_scale;
      }
    }

    // online softmax per frag-row (16-lane row groups; shfl_xor 1/2/4/8)
#pragma unroll
    for (int f = 0; f < 2; f++) {
#pragma unroll
      for (int r = 0; r < 4; r++) {
        float mx = fmaxf(fmaxf(s[f][0][r], s[f][1][r]),
                         fmaxf(s[f][2][r], s[f][3][r]));
        mx = fmaxf(mx, __shfl_xor(mx, 1));
        mx = fmaxf(mx, __shfl_xor(mx, 2));
        mx = fmaxf(mx, __shfl_xor(mx, 4));
        mx = fmaxf(mx, __shfl_xor(mx, 8));
        const float mo = m_r[f][r];
        const float mn = fmaxf(mo, mx);
        m_r[f][r] = mn;
        const float alpha = __expf(mo - mn);
        float rs = 0.f;
#pragma unroll
        for (int fj = 0; fj < 4; fj++) {
          const float p = __expf(s[f][fj][r] - mn);
          rs += p;
          Ps[wv * 32 + f * 16 + quad * 4 + r][fj * 16 + l16] = __float2bfloat16(p);
        }
        rs += __shfl_xor(rs, 1);
        rs += __shfl_xor(rs, 2);
        rs += __shfl_xor(rs, 4);
        rs += __shfl_xor(rs, 8);
        l_r[f][r] = alpha * l_r[f][r] + rs;
#pragma unroll
        for (int fd = 0; fd < 4; fd++) o[f][fd][r] *= alpha;
      }
    }

    // O += P V  (Ps rows wave-private; lgkmcnt ordering handles RAW)
    short8 ap[2][2];
#pragma unroll
    for (int f = 0; f < 2; f++) {
      ap[f][0] = *(const short8*)&Ps[wv * 32 + f * 16 + l16][quad * 8];
      ap[f][1] = *(const short8*)&Ps[wv * 32 + f * 16 + l16][32 + quad * 8];
    }
#pragma unroll
    for (int fd = 0; fd < 4; fd++) {
      short8 bv0 = *(const short8*)&Vt[fd * 16 + l16][quad * 8];
      short8 bv1 = *(const short8*)&Vt[fd * 16 + l16][32 + quad * 8];
#pragma unroll
      for (int f = 0; f < 2; f++) {
        o[f][fd] = __builtin_amdgcn_mfma_f32_16x16x32_bf16(ap[f][0], bv0, o[f][fd], 0, 0, 0);
        o[f][fd] = __builtin_amdgcn_mfma_f32_16x16x32_bf16(ap[f][1], bv1, o[f][fd], 0, 0, 0);
      }
    }
  }

#pragma unroll
  for (int f = 0; f < 2; f++) {
#pragma unroll
    for (int r = 0; r < 4; r++) {
      const float sc = out_scale / l_r[f][r];
      const size_t base =
          ((size_t)(b * S_ + qb + wv * 32 + f * 16 + quad * 4 + r)) * D_ + h * DH_;
#pragma unroll
      for (int fd = 0; fd < 4; fd++)
        att[base + fd * 16 + l16] = __float2bfloat16(o[f][fd][r] * sc);
    }
  }
}

// ---------------------------------------------------------------------------
extern "C" void kernel_launch(void* const* d_in, const int* in_sizes, int n_in,
                              void* d_out, int out_size, void* d_ws, size_t ws_size,
                              hipStream_t stream) {
  const float* x     = (const float*)d_in[0];
  const float* w_qkv = (const float*)d_in[1];
  const float* w_o   = (const float*)d_in[2];
  const float* w1    = (const float*)d_in[3];
  const float* b1    = (const float*)d_in[4];
  const float* w2    = (const float*)d_in[5];
  const float* b2    = (const float*)d_in[6];
  const float* ln1w  = (const float*)d_in[7];
  const float* ln1b  = (const float*)d_in[8];
  const float* ln2w  = (const float*)d_in[9];
  const float* ln2b  = (const float*)d_in[10];
  float* out = (float*)d_out;
  bf16* ws  = (bf16*)d_ws;

  // workspace layout (bf16 elements), with reuse (peak 29,360,128 els = 58.7 MB)
  bf16* h1       = ws;                 // LN1 out; dead after QKV gemm
  bf16* Qb       = ws + 4194304;
  bf16* Kb       = ws + 8388608;
  bf16* Vb       = ws + 12582912;      // Q/K/V dead after flash
  bf16* qkv      = ws + 16777216;      // dead after extract
  bf16* att      = ws;                 // = h1 region
  bf16* attn_out = ws + 16777216;      // dead after LN2
  bf16* x2       = ws + 20971520;
  bf16* h2       = ws + 25165824;
  bf16* g        = ws;                 // h1+Q/K/V regions (dead)
  bf16* wqb      = ws + 4194304;       // overwritten by extract (ok)
  bf16* wob      = ws + 4194304;       // Q region, dead after flash
  bf16* w1b      = ws + 16777216;      // attn_out region, dead
  bf16* w2b      = ws + 16777216;      // w1b dead after FFN1

  const float MM_SCALE   = (float)pow((double)S_ * S_ * DH_, -1.0 / 6.0);
  const float SM_SCALE   = (float)((double)S_ / sqrt(1.31 * 1.65));
  const float GELU_SCALE = (float)pow(0.588 * 0.675, -0.5);
  const float SQRT_TAU   = (float)sqrt(0.2);
  const float SQRT_1MT   = (float)sqrt(0.8);
  const float qkv_scale  = (float)pow((double)D_ * D3_, -0.25);
  const float o_scale    = (float)pow((double)D_ * D_, -0.25);
  const float w1_scale   = (float)pow((double)D_ * DF_, -0.25);
  const float w2_scale   = (float)pow((double)DF_ * D_, -0.25);

  // 1. LN1
  resid_ln_kernel<false, float, float><<<BS_, 256, 0, stream>>>(
      x, nullptr, ln1w, ln1b, nullptr, h1, 0.f, 0.f);
  // 2. convert w_qkv; QKV gemm (768 blocks)
  cvt_f32_bf16<<<(D3_ * D_ / 4 + 255) / 256, 256, 0, stream>>>(w_qkv, wqb, D3_ * D_ / 4);
  gemm_mfma<0, 128, 128, bf16><<<dim3(D3_ / 128, BS_ / 128), 256, 0, stream>>>(
      h1, wqb, qkv, BS_, D3_, D_, qkv_scale, nullptr, nullptr, 0.f, 0.f);
  // 3. de-interleave
  extract_qkv<<<(3 * BS_ * D_) / 256, 256, 0, stream>>>(qkv, Qb);
  // 4. MFMA flash attention (512 blocks)
  flash_attn_mfma<<<dim3(S_ / 128, H_, B_), 256, 0, stream>>>(
      Qb, Kb, Vb, att, MM_SCALE, SM_SCALE * MM_SCALE);
  // 5. convert w_o; out-proj (BM=64 -> 512 blocks)
  cvt_f32_bf16<<<(D_ * D_ / 4 + 255) / 256, 256, 0, stream>>>(w_o, wob, D_ * D_ / 4);
  gemm_mfma<0, 64, 128, bf16><<<dim3(D_ / 128, BS_ / 64), 256, 0, stream>>>(
      att, wob, attn_out, BS_, D_, D_, o_scale, nullptr, nullptr, 0.f, 0.f);
  // 6. residual + LN2
  resid_ln_kernel<true, bf16, float><<<BS_, 256, 0, stream>>>(
      attn_out, x, ln2w, ln2b, x2, h2, SQRT_TAU, SQRT_1MT);
  // 7. convert w1; FFN1 + GELU (1024 blocks)
  cvt_f32_bf16<<<(DF_ * D_ / 4 + 255) / 256, 256, 0, stream>>>(w1, w1b, DF_ * D_ / 4);
  gemm_mfma<1, 128, 128, bf16><<<dim3(DF_ / 128, BS_ / 128), 256, 0, stream>>>(
      h2, w1b, g, BS_, DF_, D_, w1_scale, b1, nullptr, GELU_SCALE, 0.f);
  // 8. convert w2; FFN2 + bias + final residual -> d_out (BM=64 -> 512 blocks)
  cvt_f32_bf16<<<(D_ * DF_ / 4 + 255) / 256, 256, 0, stream>>>(w2, w2b, D_ * DF_ / 4);
  gemm_mfma<2, 64, 128, float><<<dim3(D_ / 128, BS_ / 64), 256, 0, stream>>>(
      g, w2b, out, BS_, D_, DF_, w2_scale, b2, x2, SQRT_TAU, SQRT_1MT);
}

// Round 8
// 473.128 us; speedup vs baseline: 1.0977x; 1.0538x over previous
//
#include <hip/hip_runtime.h>
#include <hip/hip_bf16.h>
#include <math.h>

typedef __hip_bfloat16 bf16;
typedef __attribute__((ext_vector_type(8))) short short8;
typedef __attribute__((ext_vector_type(4))) float floatx4;

#define B_   2
#define S_   2048
#define D_   1024
#define H_   16
#define DH_  64
#define BS_  4096   // B_*S_
#define D3_  3072   // 3*D_
#define DF_  4096   // 4*D_

__device__ __forceinline__ float tof(float v) { return v; }
__device__ __forceinline__ float tof(bf16 v) { return __bfloat162float(v); }
__device__ __forceinline__ void stf(float* p, size_t i, float v) { p[i] = v; }
__device__ __forceinline__ void stf(bf16* p, size_t i, float v) { p[i] = __float2bfloat16(v); }

// async global->LDS 16B copy: lane's data lands at readfirstlane(lds)+lane*16
__device__ __forceinline__ void gload_lds16(const bf16* g, bf16* l) {
  __builtin_amdgcn_global_load_lds(
      (const __attribute__((address_space(1))) unsigned int*)g,
      (__attribute__((address_space(3))) unsigned int*)l, 16, 0, 0);
}

// ---------------------------------------------------------------------------
// fp32 -> bf16 weight conversion (vectorized x4)
// ---------------------------------------------------------------------------
__global__ __launch_bounds__(256) void cvt_f32_bf16(
    const float* __restrict__ in, bf16* __restrict__ out, int n4) {
  int i = blockIdx.x * 256 + threadIdx.x;
  if (i >= n4) return;
  float4 v = ((const float4*)in)[i];
  bf16 o[4] = {__float2bfloat16(v.x), __float2bfloat16(v.y),
               __float2bfloat16(v.z), __float2bfloat16(v.w)};
  ((ulong1*)out)[i] = *(ulong1*)o;
}

// ---------------------------------------------------------------------------
// LayerNorm (optionally fused with residual add): one block per row of D_=1024
// ---------------------------------------------------------------------------
template <bool FUSE, typename TA, typename TS>
__global__ __launch_bounds__(256) void resid_ln_kernel(
    const TA* __restrict__ a, const TS* __restrict__ skip,
    const float* __restrict__ w, const float* __restrict__ bias,
    bf16* __restrict__ x2, bf16* __restrict__ hout, float st, float s1t) {
  const int row = blockIdx.x;
  const int tid = threadIdx.x;
  const int base = tid * 4;
  const size_t roff = (size_t)row * D_;

  float xv[4];
#pragma unroll
  for (int i = 0; i < 4; i++) {
    float v = tof(a[roff + base + i]);
    if (FUSE) v = st * v + s1t * tof(skip[roff + base + i]);
    xv[i] = v;
  }
  if (FUSE) {
#pragma unroll
    for (int i = 0; i < 4; i++) x2[roff + base + i] = __float2bfloat16(xv[i]);
  }

  float ls = 0.f, lq = 0.f;
#pragma unroll
  for (int i = 0; i < 4; i++) { ls += xv[i]; lq += xv[i] * xv[i]; }

  __shared__ float ssum[256];
  __shared__ float ssq[256];
  ssum[tid] = ls; ssq[tid] = lq;
  __syncthreads();
  for (int off = 128; off > 0; off >>= 1) {
    if (tid < off) { ssum[tid] += ssum[tid + off]; ssq[tid] += ssq[tid + off]; }
    __syncthreads();
  }
  const float mean = ssum[0] * (1.0f / D_);
  const float var  = ssq[0] * (1.0f / D_) - mean * mean;
  const float rstd = rsqrtf(var + 1e-5f);

#pragma unroll
  for (int i = 0; i < 4; i++) {
    float v = (xv[i] - mean) * rstd * w[base + i] + bias[base + i];
    hout[roff + base + i] = __float2bfloat16(v);
  }
}

// ---------------------------------------------------------------------------
// MFMA GEMM: C[M,N] = epilogue( A[M,K] @ Bw[N,K]^T ), both bf16.
// BM x BN tile, BK=32, 4 waves 2x2; wave = (BM/2)x(BN/2), frags of 16x16x32.
// ---------------------------------------------------------------------------
template <int EPI, int BM, int BN, typename TC>
__global__ __launch_bounds__(256) void gemm_mfma(
    const bf16* __restrict__ A, const bf16* __restrict__ Bw,
    TC* __restrict__ C, int M, int N, int K, float scale,
    const float* __restrict__ bias, const bf16* __restrict__ resid,
    float st, float s1t) {
  constexpr int FI = BM / 32;
  constexpr int FJ = BN / 32;
  constexpr int NA = BM * 4 / 256;
  constexpr int NB = BN * 4 / 256;

  __shared__ __align__(16) bf16 As[BM][32];
  __shared__ __align__(16) bf16 Bs[BN][32];

  const int tid = threadIdx.x;
  const int lane = tid & 63;
  const int w = tid >> 6;
  const int wm = (w >> 1) * (BM / 2);
  const int wn = (w & 1) * (BN / 2);
  const int quad = lane >> 4;
  const int l16 = lane & 15;
  const int bm = blockIdx.y * BM, bn = blockIdx.x * BN;

  floatx4 acc[FI][FJ];
#pragma unroll
  for (int i = 0; i < FI; i++)
#pragma unroll
    for (int j = 0; j < FJ; j++) acc[i][j] = {0.f, 0.f, 0.f, 0.f};

  const bf16* Ap[NA];
  bf16* lA[NA];
#pragma unroll
  for (int i = 0; i < NA; i++) {
    const int c = tid + i * 256;
    Ap[i] = A + (size_t)(bm + (c >> 2)) * K + (c & 3) * 8;
    lA[i] = (bf16*)As + (size_t)c * 8;
  }
  const bf16* Bp[NB];
  bf16* lB[NB];
#pragma unroll
  for (int i = 0; i < NB; i++) {
    const int c = tid + i * 256;
    Bp[i] = Bw + (size_t)(bn + (c >> 2)) * K + (c & 3) * 8;
    lB[i] = (bf16*)Bs + (size_t)c * 8;
  }

  for (int k0 = 0; k0 < K; k0 += 32) {
    __syncthreads();
#pragma unroll
    for (int i = 0; i < NA; i++) gload_lds16(Ap[i] + k0, lA[i]);
#pragma unroll
    for (int i = 0; i < NB; i++) gload_lds16(Bp[i] + k0, lB[i]);
    __syncthreads();

    short8 af[FI], bf[FJ];
#pragma unroll
    for (int f = 0; f < FI; f++)
      af[f] = *(const short8*)&As[wm + f * 16 + l16][quad * 8];
#pragma unroll
    for (int f = 0; f < FJ; f++)
      bf[f] = *(const short8*)&Bs[wn + f * 16 + l16][quad * 8];
#pragma unroll
    for (int fi = 0; fi < FI; fi++)
#pragma unroll
      for (int fj = 0; fj < FJ; fj++)
        acc[fi][fj] = __builtin_amdgcn_mfma_f32_16x16x32_bf16(
            af[fi], bf[fj], acc[fi][fj], 0, 0, 0);
  }

#pragma unroll
  for (int fi = 0; fi < FI; fi++) {
#pragma unroll
    for (int fj = 0; fj < FJ; fj++) {
      const int col = bn + wn + fj * 16 + l16;
#pragma unroll
      for (int r = 0; r < 4; r++) {
        const int row = bm + wm + fi * 16 + quad * 4 + r;
        float v = acc[fi][fj][r];
        if (EPI == 0) {
          v *= scale;
        } else if (EPI == 1) {
          v = (v + bias[col]) * scale;
          v = 0.5f * v * (1.0f + erff(v * 0.70710678118654752f)) * st;
        } else {
          v = (v + bias[col]) * scale;
          v = st * v + s1t * __bfloat162float(resid[(size_t)row * N + col]);
        }
        stf(C, (size_t)row * N + col, v);
      }
    }
  }
}

// ---------------------------------------------------------------------------
// De-interleave qkv: qkv[b,s, d*48 + z*16 + h] -> QKV[z][b][h][s][d]
// ---------------------------------------------------------------------------
__global__ __launch_bounds__(256) void extract_qkv(
    const bf16* __restrict__ qkv, bf16* __restrict__ QKV) {
  size_t i = (size_t)blockIdx.x * 256 + threadIdx.x;
  const int d = (int)(i & 63);
  size_t r = i >> 6;
  const int ss = (int)(r & (S_ - 1)); r >>= 11;
  const int hh = (int)(r & (H_ - 1)); r >>= 4;
  const int bb = (int)(r & 1);
  const int z  = (int)(r >> 1);
  const int row = bb * S_ + ss;
  const int col = d * 48 + z * 16 + hh;
  QKV[i] = qkv[(size_t)row * D3_ + col];
}

// ---------------------------------------------------------------------------
// MFMA flash attention, S^T scheme. Block = (128 Q-rows, head, batch), 4 waves.
// Wave owns 32 queries as 2 COLUMN-frags: S^T = K·Q^T via mfma(K-frag, Q-frag)
// -> C[key][query], col=query=l16. Row stats per query are in-lane reductions
// over 16 register values + shfl_xor(16,32) across quads. P written to LDS as
// [query][key]; PV identical to previous rounds (verified).
// sc2 = MM_SCALE*log2(e); exp via exp2f (1 v_exp, no mul).
// ---------------------------------------------------------------------------
__global__ __launch_bounds__(256) void flash_attn_mfma(
    const bf16* __restrict__ Q, const bf16* __restrict__ K,
    const bf16* __restrict__ V, bf16* __restrict__ att,
    float sc2, float out_scale) {
  const int qb = blockIdx.x * 128;
  const int h = blockIdx.y, b = blockIdx.z;
  const int bh = b * H_ + h;
  const int tid = threadIdx.x;
  const int lane = tid & 63;
  const int wv = tid >> 6;
  const int quad = lane >> 4;
  const int l16 = lane & 15;

  __shared__ __align__(16) bf16 Ks[64][72];
  __shared__ __align__(16) bf16 Vt[64][72];   // Vt[d][j] = V[j][d]
  __shared__ __align__(16) bf16 Ps[128][68];  // P [query][key]

  const bf16* Qb_ = Q + (size_t)bh * S_ * DH_;
  const bf16* Kb_ = K + (size_t)bh * S_ * DH_;
  const bf16* Vb_ = V + (size_t)bh * S_ * DH_;

  // Q as B-operand frags: frag f = queries qb + wv*32 + f*16 + l16
  short8 bq[2][2];
#pragma unroll
  for (int f = 0; f < 2; f++) {
    const bf16* qrow = Qb_ + (size_t)(qb + wv * 32 + f * 16 + l16) * DH_ + quad * 8;
    bq[f][0] = *(const short8*)(qrow);
    bq[f][1] = *(const short8*)(qrow + 32);
  }

  float m_r[2] = {-1e30f, -1e30f};
  float l_r[2] = {0.f, 0.f};
  floatx4 o[2][4];
#pragma unroll
  for (int f = 0; f < 2; f++)
#pragma unroll
    for (int fd = 0; fd < 4; fd++) o[f][fd] = {0.f, 0.f, 0.f, 0.f};

  const int kr0 = tid >> 3, ko0 = (tid & 7) * 8;
  const int kr1 = (tid + 256) >> 3;
  const int vj0 = tid & 63, vd0 = (tid >> 6) * 8;
  const int vd1 = ((tid + 256) >> 6) * 8;

  for (int t = 0; t < S_ / 64; t++) {
    __syncthreads();
    *(uint4*)&Ks[kr0][ko0] = *(const uint4*)(Kb_ + (size_t)(t * 64 + kr0) * DH_ + ko0);
    *(uint4*)&Ks[kr1][ko0] = *(const uint4*)(Kb_ + (size_t)(t * 64 + kr1) * DH_ + ko0);
    {
      bf16 tmp[8];
      *(uint4*)tmp = *(const uint4*)(Vb_ + (size_t)(t * 64 + vj0) * DH_ + vd0);
#pragma unroll
      for (int e = 0; e < 8; e++) Vt[vd0 + e][vj0] = tmp[e];
      *(uint4*)tmp = *(const uint4*)(Vb_ + (size_t)(t * 64 + vj0) * DH_ + vd1);
#pragma unroll
      for (int e = 0; e < 8; e++) Vt[vd1 + e][vj0] = tmp[e];
    }
    __syncthreads();

    // S^T = K Q^T : C[key][query]; lane holds, per query-frag f, keys
    // fk*16 + quad*4 + r for its query f*16+l16.  Scaled into log2 domain.
    float st[2][4][4];
#pragma unroll
    for (int fk = 0; fk < 4; fk++) {
      short8 ak0 = *(const short8*)&Ks[fk * 16 + l16][quad * 8];
      short8 ak1 = *(const short8*)&Ks[fk * 16 + l16][32 + quad * 8];
#pragma unroll
      for (int f = 0; f < 2; f++) {
        floatx4 acc = {0.f, 0.f, 0.f, 0.f};
        acc = __builtin_amdgcn_mfma_f32_16x16x32_bf16(ak0, bq[f][0], acc, 0, 0, 0);
        acc = __builtin_amdgcn_mfma_f32_16x16x32_bf16(ak1, bq[f][1], acc, 0, 0, 0);
#pragma unroll
        for (int r = 0; r < 4; r++) st[f][fk][r] = acc[r] * sc2;
      }
    }

    // online softmax per query (in-lane over 16 keys, then quads via xor16/32)
    float alpha[2];
#pragma unroll
    for (int f = 0; f < 2; f++) {
      float mx = st[f][0][0];
#pragma unroll
      for (int fk = 0; fk < 4; fk++)
#pragma unroll
        for (int r = 0; r < 4; r++) mx = fmaxf(mx, st[f][fk][r]);
      mx = fmaxf(mx, __shfl_xor(mx, 16));
      mx = fmaxf(mx, __shfl_xor(mx, 32));
      const float mn = fmaxf(m_r[f], mx);
      alpha[f] = exp2f(m_r[f] - mn);
      m_r[f] = mn;
      float rs = 0.f;
#pragma unroll
      for (int fk = 0; fk < 4; fk++) {
        bf16 pk[4];
#pragma unroll
        for (int r = 0; r < 4; r++) {
          const float p = exp2f(st[f][fk][r] - mn);
          rs += p;
          pk[r] = __float2bfloat16(p);
        }
        *(uint2*)&Ps[wv * 32 + f * 16 + l16][fk * 16 + quad * 4] = *(uint2*)pk;
      }
      rs += __shfl_xor(rs, 16);
      rs += __shfl_xor(rs, 32);
      l_r[f] = alpha[f] * l_r[f] + rs;
    }

    // rescale O: row r of O frag = query quad*4+r; fetch its alpha via bpermute
#pragma unroll
    for (int f = 0; f < 2; f++) {
#pragma unroll
      for (int r = 0; r < 4; r++) {
        const float a = __shfl(alpha[f], quad * 20 + r, 64);
#pragma unroll
        for (int fd = 0; fd < 4; fd++) o[f][fd][r] *= a;
      }
    }

    // O += P V  (Ps rows wave-private; lgkmcnt ordering handles RAW)
    short8 ap[2][2];
#pragma unroll
    for (int f = 0; f < 2; f++) {
      ap[f][0] = *(const short8*)&Ps[wv * 32 + f * 16 + l16][quad * 8];
      ap[f][1] = *(const short8*)&Ps[wv * 32 + f * 16 + l16][32 + quad * 8];
    }
#pragma unroll
    for (int fd = 0; fd < 4; fd++) {
      short8 bv0 = *(const short8*)&Vt[fd * 16 + l16][quad * 8];
      short8 bv1 = *(const short8*)&Vt[fd * 16 + l16][32 + quad * 8];
#pragma unroll
      for (int f = 0; f < 2; f++) {
        o[f][fd] = __builtin_amdgcn_mfma_f32_16x16x32_bf16(ap[f][0], bv0, o[f][fd], 0, 0, 0);
        o[f][fd] = __builtin_amdgcn_mfma_f32_16x16x32_bf16(ap[f][1], bv1, o[f][fd], 0, 0, 0);
      }
    }
  }

  // epilogue: per O row, query = f*16 + quad*4 + r; its l via bpermute
#pragma unroll
  for (int f = 0; f < 2; f++) {
#pragma unroll
    for (int r = 0; r < 4; r++) {
      const float lq = __shfl(l_r[f], quad * 20 + r, 64);
      const float sc = out_scale / lq;
      const size_t base =
          ((size_t)(b * S_ + qb + wv * 32 + f * 16 + quad * 4 + r)) * D_ + h * DH_;
#pragma unroll
      for (int fd = 0; fd < 4; fd++)
        att[base + fd * 16 + l16] = __float2bfloat16(o[f][fd][r] * sc);
    }
  }
}

// ---------------------------------------------------------------------------
extern "C" void kernel_launch(void* const* d_in, const int* in_sizes, int n_in,
                              void* d_out, int out_size, void* d_ws, size_t ws_size,
                              hipStream_t stream) {
  const float* x     = (const float*)d_in[0];
  const float* w_qkv = (const float*)d_in[1];
  const float* w_o   = (const float*)d_in[2];
  const float* w1    = (const float*)d_in[3];
  const float* b1    = (const float*)d_in[4];
  const float* w2    = (const float*)d_in[5];
  const float* b2    = (const float*)d_in[6];
  const float* ln1w  = (const float*)d_in[7];
  const float* ln1b  = (const float*)d_in[8];
  const float* ln2w  = (const float*)d_in[9];
  const float* ln2b  = (const float*)d_in[10];
  float* out = (float*)d_out;
  bf16* ws  = (bf16*)d_ws;

  // workspace layout (bf16 elements), with reuse (peak 29,360,128 els = 58.7 MB)
  bf16* h1       = ws;                 // LN1 out; dead after QKV gemm
  bf16* Qb       = ws + 4194304;
  bf16* Kb       = ws + 8388608;
  bf16* Vb       = ws + 12582912;      // Q/K/V dead after flash
  bf16* qkv      = ws + 16777216;      // dead after extract
  bf16* att      = ws;                 // = h1 region
  bf16* attn_out = ws + 16777216;      // dead after LN2
  bf16* x2       = ws + 20971520;
  bf16* h2       = ws + 25165824;
  bf16* g        = ws;                 // h1+Q/K/V regions (dead)
  bf16* wqb      = ws + 4194304;       // overwritten by extract (ok)
  bf16* wob      = ws + 4194304;       // Q region, dead after flash
  bf16* w1b      = ws + 16777216;      // attn_out region, dead
  bf16* w2b      = ws + 16777216;      // w1b dead after FFN1

  const float MM_SCALE   = (float)pow((double)S_ * S_ * DH_, -1.0 / 6.0);
  const float SM_SCALE   = (float)((double)S_ / sqrt(1.31 * 1.65));
  const float GELU_SCALE = (float)pow(0.588 * 0.675, -0.5);
  const float SQRT_TAU   = (float)sqrt(0.2);
  const float SQRT_1MT   = (float)sqrt(0.8);
  const float LOG2E      = 1.4426950408889634f;
  const float qkv_scale  = (float)pow((double)D_ * D3_, -0.25);
  const float o_scale    = (float)pow((double)D_ * D_, -0.25);
  const float w1_scale   = (float)pow((double)D_ * DF_, -0.25);
  const float w2_scale   = (float)pow((double)DF_ * D_, -0.25);

  // 1. LN1
  resid_ln_kernel<false, float, float><<<BS_, 256, 0, stream>>>(
      x, nullptr, ln1w, ln1b, nullptr, h1, 0.f, 0.f);
  // 2. convert w_qkv; QKV gemm (768 blocks)
  cvt_f32_bf16<<<(D3_ * D_ / 4 + 255) / 256, 256, 0, stream>>>(w_qkv, wqb, D3_ * D_ / 4);
  gemm_mfma<0, 128, 128, bf16><<<dim3(D3_ / 128, BS_ / 128), 256, 0, stream>>>(
      h1, wqb, qkv, BS_, D3_, D_, qkv_scale, nullptr, nullptr, 0.f, 0.f);
  // 3. de-interleave
  extract_qkv<<<(3 * BS_ * D_) / 256, 256, 0, stream>>>(qkv, Qb);
  // 4. MFMA flash attention (512 blocks), scores in log2 domain
  flash_attn_mfma<<<dim3(S_ / 128, H_, B_), 256, 0, stream>>>(
      Qb, Kb, Vb, att, MM_SCALE * LOG2E, SM_SCALE * MM_SCALE);
  // 5. convert w_o; out-proj (BM=64 -> 512 blocks)
  cvt_f32_bf16<<<(D_ * D_ / 4 + 255) / 256, 256, 0, stream>>>(w_o, wob, D_ * D_ / 4);
  gemm_mfma<0, 64, 128, bf16><<<dim3(D_ / 128, BS_ / 64), 256, 0, stream>>>(
      att, wob, attn_out, BS_, D_, D_, o_scale, nullptr, nullptr, 0.f, 0.f);
  // 6. residual + LN2
  resid_ln_kernel<true, bf16, float><<<BS_, 256, 0, stream>>>(
      attn_out, x, ln2w, ln2b, x2, h2, SQRT_TAU, SQRT_1MT);
  // 7. convert w1; FFN1 + GELU (1024 blocks)
  cvt_f32_bf16<<<(DF_ * D_ / 4 + 255) / 256, 256, 0, stream>>>(w1, w1b, DF_ * D_ / 4);
  gemm_mfma<1, 128, 128, bf16><<<dim3(DF_ / 128, BS_ / 128), 256, 0, stream>>>(
      h2, w1b, g, BS_, DF_, D_, w1_scale, b1, nullptr, GELU_SCALE, 0.f);
  // 8. convert w2; FFN2 + bias + final residual -> d_out (BM=64 -> 512 blocks)
  cvt_f32_bf16<<<(D_ * DF_ / 4 + 255) / 256, 256, 0, stream>>>(w2, w2b, D_ * DF_ / 4);
  gemm_mfma<2, 64, 128, float><<<dim3(D_ / 128, BS_ / 64), 256, 0, stream>>>(
      g, w2b, out, BS_, D_, DF_, w2_scale, b2, x2, SQRT_TAU, SQRT_1MT);
}

// Round 9
// 467.851 us; speedup vs baseline: 1.1101x; 1.0113x over previous
//
#include <hip/hip_runtime.h>
#include <hip/hip_bf16.h>
#include <math.h>

typedef __hip_bfloat16 bf16;
typedef __attribute__((ext_vector_type(8))) short short8;
typedef __attribute__((ext_vector_type(4))) float floatx4;

#define B_   2
#define S_   2048
#define D_   1024
#define H_   16
#define DH_  64
#define BS_  4096   // B_*S_
#define D3_  3072   // 3*D_
#define DF_  4096   // 4*D_

__device__ __forceinline__ float tof(float v) { return v; }
__device__ __forceinline__ float tof(bf16 v) { return __bfloat162float(v); }
__device__ __forceinline__ void stf(float* p, size_t i, float v) { p[i] = v; }
__device__ __forceinline__ void stf(bf16* p, size_t i, float v) { p[i] = __float2bfloat16(v); }

// async global->LDS 16B copy: lane's data lands at readfirstlane(lds)+lane*16
__device__ __forceinline__ void gload_lds16(const bf16* g, bf16* l) {
  __builtin_amdgcn_global_load_lds(
      (const __attribute__((address_space(1))) unsigned int*)g,
      (__attribute__((address_space(3))) unsigned int*)l, 16, 0, 0);
}

// ---------------------------------------------------------------------------
// fp32 -> bf16 weight conversion (vectorized x4)
// ---------------------------------------------------------------------------
__global__ __launch_bounds__(256) void cvt_f32_bf16(
    const float* __restrict__ in, bf16* __restrict__ out, int n4) {
  int i = blockIdx.x * 256 + threadIdx.x;
  if (i >= n4) return;
  float4 v = ((const float4*)in)[i];
  bf16 o[4] = {__float2bfloat16(v.x), __float2bfloat16(v.y),
               __float2bfloat16(v.z), __float2bfloat16(v.w)};
  ((ulong1*)out)[i] = *(ulong1*)o;
}

// ---------------------------------------------------------------------------
// LayerNorm (optionally fused with residual add): one block per row of D_=1024
// ---------------------------------------------------------------------------
template <bool FUSE, typename TA, typename TS>
__global__ __launch_bounds__(256) void resid_ln_kernel(
    const TA* __restrict__ a, const TS* __restrict__ skip,
    const float* __restrict__ w, const float* __restrict__ bias,
    bf16* __restrict__ x2, bf16* __restrict__ hout, float st, float s1t) {
  const int row = blockIdx.x;
  const int tid = threadIdx.x;
  const int base = tid * 4;
  const size_t roff = (size_t)row * D_;

  float xv[4];
#pragma unroll
  for (int i = 0; i < 4; i++) {
    float v = tof(a[roff + base + i]);
    if (FUSE) v = st * v + s1t * tof(skip[roff + base + i]);
    xv[i] = v;
  }
  if (FUSE) {
#pragma unroll
    for (int i = 0; i < 4; i++) x2[roff + base + i] = __float2bfloat16(xv[i]);
  }

  float ls = 0.f, lq = 0.f;
#pragma unroll
  for (int i = 0; i < 4; i++) { ls += xv[i]; lq += xv[i] * xv[i]; }

  __shared__ float ssum[256];
  __shared__ float ssq[256];
  ssum[tid] = ls; ssq[tid] = lq;
  __syncthreads();
  for (int off = 128; off > 0; off >>= 1) {
    if (tid < off) { ssum[tid] += ssum[tid + off]; ssq[tid] += ssq[tid + off]; }
    __syncthreads();
  }
  const float mean = ssum[0] * (1.0f / D_);
  const float var  = ssq[0] * (1.0f / D_) - mean * mean;
  const float rstd = rsqrtf(var + 1e-5f);

#pragma unroll
  for (int i = 0; i < 4; i++) {
    float v = (xv[i] - mean) * rstd * w[base + i] + bias[base + i];
    hout[roff + base + i] = __float2bfloat16(v);
  }
}

// ---------------------------------------------------------------------------
// MFMA GEMM: C[M,N] = epilogue( A[M,K] @ Bw[N,K]^T ), both bf16.
// BM x BN tile, BK=64 (one barrier pair per 64-K), 4 waves 2x2.
// ---------------------------------------------------------------------------
template <int EPI, int BM, int BN, typename TC>
__global__ __launch_bounds__(256) void gemm_mfma(
    const bf16* __restrict__ A, const bf16* __restrict__ Bw,
    TC* __restrict__ C, int M, int N, int K, float scale,
    const float* __restrict__ bias, const bf16* __restrict__ resid,
    float st, float s1t) {
  constexpr int FI = BM / 32;
  constexpr int FJ = BN / 32;
  constexpr int NA = BM * 8 / 256;  // 16B chunks per thread for A (BK=64)
  constexpr int NB = BN * 8 / 256;

  __shared__ __align__(16) bf16 As[BM][64];
  __shared__ __align__(16) bf16 Bs[BN][64];

  const int tid = threadIdx.x;
  const int lane = tid & 63;
  const int w = tid >> 6;
  const int wm = (w >> 1) * (BM / 2);
  const int wn = (w & 1) * (BN / 2);
  const int quad = lane >> 4;
  const int l16 = lane & 15;
  const int bm = blockIdx.y * BM, bn = blockIdx.x * BN;

  floatx4 acc[FI][FJ];
#pragma unroll
  for (int i = 0; i < FI; i++)
#pragma unroll
    for (int j = 0; j < FJ; j++) acc[i][j] = {0.f, 0.f, 0.f, 0.f};

  // chunk c (0..BM*8-1) -> row c>>3, elem-offset (c&7)*8; LDS byte = c*16
  const bf16* Ap[NA];
  bf16* lA[NA];
#pragma unroll
  for (int i = 0; i < NA; i++) {
    const int c = tid + i * 256;
    Ap[i] = A + (size_t)(bm + (c >> 3)) * K + (c & 7) * 8;
    lA[i] = (bf16*)As + (size_t)c * 8;
  }
  const bf16* Bp[NB];
  bf16* lB[NB];
#pragma unroll
  for (int i = 0; i < NB; i++) {
    const int c = tid + i * 256;
    Bp[i] = Bw + (size_t)(bn + (c >> 3)) * K + (c & 7) * 8;
    lB[i] = (bf16*)Bs + (size_t)c * 8;
  }

  for (int k0 = 0; k0 < K; k0 += 64) {
    __syncthreads();
#pragma unroll
    for (int i = 0; i < NA; i++) gload_lds16(Ap[i] + k0, lA[i]);
#pragma unroll
    for (int i = 0; i < NB; i++) gload_lds16(Bp[i] + k0, lB[i]);
    __syncthreads();

#pragma unroll
    for (int kc = 0; kc < 2; kc++) {
      short8 af[FI], bf[FJ];
#pragma unroll
      for (int f = 0; f < FI; f++)
        af[f] = *(const short8*)&As[wm + f * 16 + l16][kc * 32 + quad * 8];
#pragma unroll
      for (int f = 0; f < FJ; f++)
        bf[f] = *(const short8*)&Bs[wn + f * 16 + l16][kc * 32 + quad * 8];
#pragma unroll
      for (int fi = 0; fi < FI; fi++)
#pragma unroll
        for (int fj = 0; fj < FJ; fj++)
          acc[fi][fj] = __builtin_amdgcn_mfma_f32_16x16x32_bf16(
              af[fi], bf[fj], acc[fi][fj], 0, 0, 0);
    }
  }

#pragma unroll
  for (int fi = 0; fi < FI; fi++) {
#pragma unroll
    for (int fj = 0; fj < FJ; fj++) {
      const int col = bn + wn + fj * 16 + l16;
#pragma unroll
      for (int r = 0; r < 4; r++) {
        const int row = bm + wm + fi * 16 + quad * 4 + r;
        float v = acc[fi][fj][r];
        if (EPI == 0) {
          v *= scale;
        } else if (EPI == 1) {
          v = (v + bias[col]) * scale;
          v = 0.5f * v * (1.0f + erff(v * 0.70710678118654752f)) * st;
        } else {
          v = (v + bias[col]) * scale;
          v = st * v + s1t * __bfloat162float(resid[(size_t)row * N + col]);
        }
        stf(C, (size_t)row * N + col, v);
      }
    }
  }
}

// ---------------------------------------------------------------------------
// De-interleave qkv: qkv[b,s, d*48 + z*16 + h] -> QKV[z][b][h][s][d]
// ---------------------------------------------------------------------------
__global__ __launch_bounds__(256) void extract_qkv(
    const bf16* __restrict__ qkv, bf16* __restrict__ QKV) {
  size_t i = (size_t)blockIdx.x * 256 + threadIdx.x;
  const int d = (int)(i & 63);
  size_t r = i >> 6;
  const int ss = (int)(r & (S_ - 1)); r >>= 11;
  const int hh = (int)(r & (H_ - 1)); r >>= 4;
  const int bb = (int)(r & 1);
  const int z  = (int)(r >> 1);
  const int row = bb * S_ + ss;
  const int col = d * 48 + z * 16 + hh;
  QKV[i] = qkv[(size_t)row * D3_ + col];
}

// ---------------------------------------------------------------------------
// MFMA flash attention, S^T scheme, 512 threads = 8 waves; wave owns 16
// queries (one B-frag). QT=128 rows/block, KT=64 keys/iter.
// S^T = K·Q^T -> C[key][query], query = l16 -> per-query stats are in-lane
// reductions over 16 keys + shfl_xor(16,32). P -> LDS [query][key] -> PV
// identical to verified rounds.
// ---------------------------------------------------------------------------
__global__ __launch_bounds__(512) void flash_attn_mfma(
    const bf16* __restrict__ Q, const bf16* __restrict__ K,
    const bf16* __restrict__ V, bf16* __restrict__ att,
    float sc2, float out_scale) {
  const int qb = blockIdx.x * 128;
  const int h = blockIdx.y, b = blockIdx.z;
  const int bh = b * H_ + h;
  const int tid = threadIdx.x;
  const int lane = tid & 63;
  const int wv = tid >> 6;           // 0..7
  const int quad = lane >> 4;
  const int l16 = lane & 15;

  __shared__ __align__(16) bf16 Ks[64][72];
  __shared__ __align__(16) bf16 Vt[64][72];   // Vt[d][j] = V[j][d]
  __shared__ __align__(16) bf16 Ps[128][68];  // P [query][key]

  const bf16* Qb_ = Q + (size_t)bh * S_ * DH_;
  const bf16* Kb_ = K + (size_t)bh * S_ * DH_;
  const bf16* Vb_ = V + (size_t)bh * S_ * DH_;

  // Q as B-operand frag: queries qb + wv*16 + l16
  short8 bq0, bq1;
  {
    const bf16* qrow = Qb_ + (size_t)(qb + wv * 16 + l16) * DH_ + quad * 8;
    bq0 = *(const short8*)(qrow);
    bq1 = *(const short8*)(qrow + 32);
  }

  float m_r = -1e30f, l_r = 0.f;
  floatx4 o[4];
#pragma unroll
  for (int fd = 0; fd < 4; fd++) o[fd] = {0.f, 0.f, 0.f, 0.f};

  // staging (512 threads): K chunk = 1 x 16B; V = 1 uint4 -> 8 b16 scatters
  const int kr = tid >> 3, ko = (tid & 7) * 8;
  const int vj = tid & 63, vd = (tid >> 6) * 8;

  for (int t = 0; t < S_ / 64; t++) {
    __syncthreads();
    *(uint4*)&Ks[kr][ko] = *(const uint4*)(Kb_ + (size_t)(t * 64 + kr) * DH_ + ko);
    {
      bf16 tmp[8];
      *(uint4*)tmp = *(const uint4*)(Vb_ + (size_t)(t * 64 + vj) * DH_ + vd);
#pragma unroll
      for (int e = 0; e < 8; e++) Vt[vd + e][vj] = tmp[e];
    }
    __syncthreads();

    // S^T = K Q^T : lane holds keys fk*16 + quad*4 + r for query wv*16+l16
    float st[4][4];
#pragma unroll
    for (int fk = 0; fk < 4; fk++) {
      short8 ak0 = *(const short8*)&Ks[fk * 16 + l16][quad * 8];
      short8 ak1 = *(const short8*)&Ks[fk * 16 + l16][32 + quad * 8];
      floatx4 acc = {0.f, 0.f, 0.f, 0.f};
      acc = __builtin_amdgcn_mfma_f32_16x16x32_bf16(ak0, bq0, acc, 0, 0, 0);
      acc = __builtin_amdgcn_mfma_f32_16x16x32_bf16(ak1, bq1, acc, 0, 0, 0);
#pragma unroll
      for (int r = 0; r < 4; r++) st[fk][r] = acc[r] * sc2;
    }

    // online softmax per query (in-lane over 16 keys, then xor16/32)
    float mx = st[0][0];
#pragma unroll
    for (int fk = 0; fk < 4; fk++)
#pragma unroll
      for (int r = 0; r < 4; r++) mx = fmaxf(mx, st[fk][r]);
    mx = fmaxf(mx, __shfl_xor(mx, 16));
    mx = fmaxf(mx, __shfl_xor(mx, 32));
    const float mn = fmaxf(m_r, mx);
    const float alpha = exp2f(m_r - mn);
    m_r = mn;
    float rs = 0.f;
#pragma unroll
    for (int fk = 0; fk < 4; fk++) {
      bf16 pk[4];
#pragma unroll
      for (int r = 0; r < 4; r++) {
        const float p = exp2f(st[fk][r] - mn);
        rs += p;
        pk[r] = __float2bfloat16(p);
      }
      *(uint2*)&Ps[wv * 16 + l16][fk * 16 + quad * 4] = *(uint2*)pk;
    }
    rs += __shfl_xor(rs, 16);
    rs += __shfl_xor(rs, 32);
    l_r = alpha * l_r + rs;

    // rescale O: row r of O frag = query quad*4+r; fetch its alpha
#pragma unroll
    for (int r = 0; r < 4; r++) {
      const float a = __shfl(alpha, quad * 20 + r, 64);
#pragma unroll
      for (int fd = 0; fd < 4; fd++) o[fd][r] *= a;
    }

    // O += P V
    short8 ap0 = *(const short8*)&Ps[wv * 16 + l16][quad * 8];
    short8 ap1 = *(const short8*)&Ps[wv * 16 + l16][32 + quad * 8];
#pragma unroll
    for (int fd = 0; fd < 4; fd++) {
      short8 bv0 = *(const short8*)&Vt[fd * 16 + l16][quad * 8];
      short8 bv1 = *(const short8*)&Vt[fd * 16 + l16][32 + quad * 8];
      o[fd] = __builtin_amdgcn_mfma_f32_16x16x32_bf16(ap0, bv0, o[fd], 0, 0, 0);
      o[fd] = __builtin_amdgcn_mfma_f32_16x16x32_bf16(ap1, bv1, o[fd], 0, 0, 0);
    }
  }

  // epilogue: O row -> query wv*16 + quad*4 + r; its l via shfl
#pragma unroll
  for (int r = 0; r < 4; r++) {
    const float lq = __shfl(l_r, quad * 20 + r, 64);
    const float sc = out_scale / lq;
    const size_t base =
        ((size_t)(b * S_ + qb + wv * 16 + quad * 4 + r)) * D_ + h * DH_;
#pragma unroll
    for (int fd = 0; fd < 4; fd++)
      att[base + fd * 16 + l16] = __float2bfloat16(o[fd][r] * sc);
  }
}

// ---------------------------------------------------------------------------
extern "C" void kernel_launch(void* const* d_in, const int* in_sizes, int n_in,
                              void* d_out, int out_size, void* d_ws, size_t ws_size,
                              hipStream_t stream) {
  const float* x     = (const float*)d_in[0];
  const float* w_qkv = (const float*)d_in[1];
  const float* w_o   = (const float*)d_in[2];
  const float* w1    = (const float*)d_in[3];
  const float* b1    = (const float*)d_in[4];
  const float* w2    = (const float*)d_in[5];
  const float* b2    = (const float*)d_in[6];
  const float* ln1w  = (const float*)d_in[7];
  const float* ln1b  = (const float*)d_in[8];
  const float* ln2w  = (const float*)d_in[9];
  const float* ln2b  = (const float*)d_in[10];
  float* out = (float*)d_out;
  bf16* ws  = (bf16*)d_ws;

  // workspace layout (bf16 elements), with reuse (peak 29,360,128 els = 58.7 MB)
  bf16* h1       = ws;                 // LN1 out; dead after QKV gemm
  bf16* Qb       = ws + 4194304;
  bf16* Kb       = ws + 8388608;
  bf16* Vb       = ws + 12582912;      // Q/K/V dead after flash
  bf16* qkv      = ws + 16777216;      // dead after extract
  bf16* att      = ws;                 // = h1 region
  bf16* attn_out = ws + 16777216;      // dead after LN2
  bf16* x2       = ws + 20971520;
  bf16* h2       = ws + 25165824;
  bf16* g        = ws;                 // h1+Q/K/V regions (dead)
  bf16* wqb      = ws + 4194304;       // overwritten by extract (ok)
  bf16* wob      = ws + 4194304;       // Q region, dead after flash
  bf16* w1b      = ws + 16777216;      // attn_out region, dead
  bf16* w2b      = ws + 16777216;      // w1b dead after FFN1

  const float MM_SCALE   = (float)pow((double)S_ * S_ * DH_, -1.0 / 6.0);
  const float SM_SCALE   = (float)((double)S_ / sqrt(1.31 * 1.65));
  const float GELU_SCALE = (float)pow(0.588 * 0.675, -0.5);
  const float SQRT_TAU   = (float)sqrt(0.2);
  const float SQRT_1MT   = (float)sqrt(0.8);
  const float LOG2E      = 1.4426950408889634f;
  const float qkv_scale  = (float)pow((double)D_ * D3_, -0.25);
  const float o_scale    = (float)pow((double)D_ * D_, -0.25);
  const float w1_scale   = (float)pow((double)D_ * DF_, -0.25);
  const float w2_scale   = (float)pow((double)DF_ * D_, -0.25);

  // 1. LN1
  resid_ln_kernel<false, float, float><<<BS_, 256, 0, stream>>>(
      x, nullptr, ln1w, ln1b, nullptr, h1, 0.f, 0.f);
  // 2. convert w_qkv; QKV gemm (768 blocks)
  cvt_f32_bf16<<<(D3_ * D_ / 4 + 255) / 256, 256, 0, stream>>>(w_qkv, wqb, D3_ * D_ / 4);
  gemm_mfma<0, 128, 128, bf16><<<dim3(D3_ / 128, BS_ / 128), 256, 0, stream>>>(
      h1, wqb, qkv, BS_, D3_, D_, qkv_scale, nullptr, nullptr, 0.f, 0.f);
  // 3. de-interleave
  extract_qkv<<<(3 * BS_ * D_) / 256, 256, 0, stream>>>(qkv, Qb);
  // 4. MFMA flash attention (512 blocks x 8 waves), scores in log2 domain
  flash_attn_mfma<<<dim3(S_ / 128, H_, B_), 512, 0, stream>>>(
      Qb, Kb, Vb, att, MM_SCALE * LOG2E, SM_SCALE * MM_SCALE);
  // 5. convert w_o; out-proj (BM=64 -> 512 blocks)
  cvt_f32_bf16<<<(D_ * D_ / 4 + 255) / 256, 256, 0, stream>>>(w_o, wob, D_ * D_ / 4);
  gemm_mfma<0, 64, 128, bf16><<<dim3(D_ / 128, BS_ / 64), 256, 0, stream>>>(
      att, wob, attn_out, BS_, D_, D_, o_scale, nullptr, nullptr, 0.f, 0.f);
  // 6. residual + LN2
  resid_ln_kernel<true, bf16, float><<<BS_, 256, 0, stream>>>(
      attn_out, x, ln2w, ln2b, x2, h2, SQRT_TAU, SQRT_1MT);
  // 7. convert w1; FFN1 + GELU (1024 blocks)
  cvt_f32_bf16<<<(DF_ * D_ / 4 + 255) / 256, 256, 0, stream>>>(w1, w1b, DF_ * D_ / 4);
  gemm_mfma<1, 128, 128, bf16><<<dim3(DF_ / 128, BS_ / 128), 256, 0, stream>>>(
      h2, w1b, g, BS_, DF_, D_, w1_scale, b1, nullptr, GELU_SCALE, 0.f);
  // 8. convert w2; FFN2 + bias + final residual -> d_out (BM=64 -> 512 blocks)
  cvt_f32_bf16<<<(D_ * DF_ / 4 + 255) / 256, 256, 0, stream>>>(w2, w2b, D_ * DF_ / 4);
  gemm_mfma<2, 64, 128, float><<<dim3(D_ / 128, BS_ / 64), 256, 0, stream>>>(
      g, w2b, out, BS_, D_, DF_, w2_scale, b2, x2, SQRT_TAU, SQRT_1MT);
}

// Round 10
// 463.790 us; speedup vs baseline: 1.1198x; 1.0088x over previous
//
#include <hip/hip_runtime.h>
#include <hip/hip_bf16.h>
#include <math.h>

typedef __hip_bfloat16 bf16;
typedef __attribute__((ext_vector_type(8))) short short8;
typedef __attribute__((ext_vector_type(4))) float floatx4;

#define B_   2
#define S_   2048
#define D_   1024
#define H_   16
#define DH_  64
#define BS_  4096   // B_*S_
#define D3_  3072   // 3*D_
#define DF_  4096   // 4*D_

__device__ __forceinline__ float tof(float v) { return v; }
__device__ __forceinline__ float tof(bf16 v) { return __bfloat162float(v); }
__device__ __forceinline__ void stf(float* p, size_t i, float v) { p[i] = v; }
__device__ __forceinline__ void stf(bf16* p, size_t i, float v) { p[i] = __float2bfloat16(v); }

// async global->LDS 16B copy: lane's data lands at readfirstlane(lds)+lane*16
__device__ __forceinline__ void gload_lds16(const bf16* g, bf16* l) {
  __builtin_amdgcn_global_load_lds(
      (const __attribute__((address_space(1))) unsigned int*)g,
      (__attribute__((address_space(3))) unsigned int*)l, 16, 0, 0);
}

// ---------------------------------------------------------------------------
// fp32 -> bf16 weight conversion (vectorized x4)
// ---------------------------------------------------------------------------
__global__ __launch_bounds__(256) void cvt_f32_bf16(
    const float* __restrict__ in, bf16* __restrict__ out, int n4) {
  int i = blockIdx.x * 256 + threadIdx.x;
  if (i >= n4) return;
  float4 v = ((const float4*)in)[i];
  bf16 o[4] = {__float2bfloat16(v.x), __float2bfloat16(v.y),
               __float2bfloat16(v.z), __float2bfloat16(v.w)};
  ((ulong1*)out)[i] = *(ulong1*)o;
}

// ---------------------------------------------------------------------------
// LayerNorm (optionally fused with residual add): one block per row of D_=1024
// ---------------------------------------------------------------------------
template <bool FUSE, typename TA, typename TS>
__global__ __launch_bounds__(256) void resid_ln_kernel(
    const TA* __restrict__ a, const TS* __restrict__ skip,
    const float* __restrict__ w, const float* __restrict__ bias,
    bf16* __restrict__ x2, bf16* __restrict__ hout, float st, float s1t) {
  const int row = blockIdx.x;
  const int tid = threadIdx.x;
  const int base = tid * 4;
  const size_t roff = (size_t)row * D_;

  float xv[4];
#pragma unroll
  for (int i = 0; i < 4; i++) {
    float v = tof(a[roff + base + i]);
    if (FUSE) v = st * v + s1t * tof(skip[roff + base + i]);
    xv[i] = v;
  }
  if (FUSE) {
#pragma unroll
    for (int i = 0; i < 4; i++) x2[roff + base + i] = __float2bfloat16(xv[i]);
  }

  float ls = 0.f, lq = 0.f;
#pragma unroll
  for (int i = 0; i < 4; i++) { ls += xv[i]; lq += xv[i] * xv[i]; }

  __shared__ float ssum[256];
  __shared__ float ssq[256];
  ssum[tid] = ls; ssq[tid] = lq;
  __syncthreads();
  for (int off = 128; off > 0; off >>= 1) {
    if (tid < off) { ssum[tid] += ssum[tid + off]; ssq[tid] += ssq[tid + off]; }
    __syncthreads();
  }
  const float mean = ssum[0] * (1.0f / D_);
  const float var  = ssq[0] * (1.0f / D_) - mean * mean;
  const float rstd = rsqrtf(var + 1e-5f);

#pragma unroll
  for (int i = 0; i < 4; i++) {
    float v = (xv[i] - mean) * rstd * w[base + i] + bias[base + i];
    hout[roff + base + i] = __float2bfloat16(v);
  }
}

// ---------------------------------------------------------------------------
// MFMA GEMM: C[M,N] = epilogue( A[M,K] @ Bw[N,K]^T ), both bf16.
// BM x BN tile, BK=64, 4 waves 2x2.
// ---------------------------------------------------------------------------
template <int EPI, int BM, int BN, typename TC>
__global__ __launch_bounds__(256) void gemm_mfma(
    const bf16* __restrict__ A, const bf16* __restrict__ Bw,
    TC* __restrict__ C, int M, int N, int K, float scale,
    const float* __restrict__ bias, const bf16* __restrict__ resid,
    float st, float s1t) {
  constexpr int FI = BM / 32;
  constexpr int FJ = BN / 32;
  constexpr int NA = BM * 8 / 256;
  constexpr int NB = BN * 8 / 256;

  __shared__ __align__(16) bf16 As[BM][64];
  __shared__ __align__(16) bf16 Bs[BN][64];

  const int tid = threadIdx.x;
  const int lane = tid & 63;
  const int w = tid >> 6;
  const int wm = (w >> 1) * (BM / 2);
  const int wn = (w & 1) * (BN / 2);
  const int quad = lane >> 4;
  const int l16 = lane & 15;
  const int bm = blockIdx.y * BM, bn = blockIdx.x * BN;

  floatx4 acc[FI][FJ];
#pragma unroll
  for (int i = 0; i < FI; i++)
#pragma unroll
    for (int j = 0; j < FJ; j++) acc[i][j] = {0.f, 0.f, 0.f, 0.f};

  const bf16* Ap[NA];
  bf16* lA[NA];
#pragma unroll
  for (int i = 0; i < NA; i++) {
    const int c = tid + i * 256;
    Ap[i] = A + (size_t)(bm + (c >> 3)) * K + (c & 7) * 8;
    lA[i] = (bf16*)As + (size_t)c * 8;
  }
  const bf16* Bp[NB];
  bf16* lB[NB];
#pragma unroll
  for (int i = 0; i < NB; i++) {
    const int c = tid + i * 256;
    Bp[i] = Bw + (size_t)(bn + (c >> 3)) * K + (c & 7) * 8;
    lB[i] = (bf16*)Bs + (size_t)c * 8;
  }

  for (int k0 = 0; k0 < K; k0 += 64) {
    __syncthreads();
#pragma unroll
    for (int i = 0; i < NA; i++) gload_lds16(Ap[i] + k0, lA[i]);
#pragma unroll
    for (int i = 0; i < NB; i++) gload_lds16(Bp[i] + k0, lB[i]);
    __syncthreads();

#pragma unroll
    for (int kc = 0; kc < 2; kc++) {
      short8 af[FI], bf[FJ];
#pragma unroll
      for (int f = 0; f < FI; f++)
        af[f] = *(const short8*)&As[wm + f * 16 + l16][kc * 32 + quad * 8];
#pragma unroll
      for (int f = 0; f < FJ; f++)
        bf[f] = *(const short8*)&Bs[wn + f * 16 + l16][kc * 32 + quad * 8];
#pragma unroll
      for (int fi = 0; fi < FI; fi++)
#pragma unroll
        for (int fj = 0; fj < FJ; fj++)
          acc[fi][fj] = __builtin_amdgcn_mfma_f32_16x16x32_bf16(
              af[fi], bf[fj], acc[fi][fj], 0, 0, 0);
    }
  }

#pragma unroll
  for (int fi = 0; fi < FI; fi++) {
#pragma unroll
    for (int fj = 0; fj < FJ; fj++) {
      const int col = bn + wn + fj * 16 + l16;
#pragma unroll
      for (int r = 0; r < 4; r++) {
        const int row = bm + wm + fi * 16 + quad * 4 + r;
        float v = acc[fi][fj][r];
        if (EPI == 0) {
          v *= scale;
        } else if (EPI == 1) {
          v = (v + bias[col]) * scale;
          v = 0.5f * v * (1.0f + erff(v * 0.70710678118654752f)) * st;
        } else {
          v = (v + bias[col]) * scale;
          v = st * v + s1t * __bfloat162float(resid[(size_t)row * N + col]);
        }
        stf(C, (size_t)row * N + col, v);
      }
    }
  }
}

// ---------------------------------------------------------------------------
// De-interleave qkv: qkv[b,s, d*48 + z*16 + h] -> QKV[z][b][h][s][d]
// ---------------------------------------------------------------------------
__global__ __launch_bounds__(256) void extract_qkv(
    const bf16* __restrict__ qkv, bf16* __restrict__ QKV) {
  size_t i = (size_t)blockIdx.x * 256 + threadIdx.x;
  const int d = (int)(i & 63);
  size_t r = i >> 6;
  const int ss = (int)(r & (S_ - 1)); r >>= 11;
  const int hh = (int)(r & (H_ - 1)); r >>= 4;
  const int bb = (int)(r & 1);
  const int z  = (int)(r >> 1);
  const int row = bb * S_ + ss;
  const int col = d * 48 + z * 16 + hh;
  QKV[i] = qkv[(size_t)row * D3_ + col];
}

// ---------------------------------------------------------------------------
// MFMA flash attention, S^T scheme, 512 threads = 8 waves, QT=128, KT=64.
// Double-buffered K/V LDS + register prefetch: iter t commits prefetched
// regs into buf[cur], ONE barrier, issues loads for t+1 (consumed next
// iter -> whole compute phase hides the load latency), computes from
// buf[cur]. Buffer reuse safe: writing buf at t+2 requires passing
// barrier(t+1), which requires all waves finished compute(t).
// ---------------------------------------------------------------------------
__global__ __launch_bounds__(512) void flash_attn_mfma(
    const bf16* __restrict__ Q, const bf16* __restrict__ K,
    const bf16* __restrict__ V, bf16* __restrict__ att,
    float sc2, float out_scale) {
  const int qb = blockIdx.x * 128;
  const int h = blockIdx.y, b = blockIdx.z;
  const int bh = b * H_ + h;
  const int tid = threadIdx.x;
  const int lane = tid & 63;
  const int wv = tid >> 6;           // 0..7
  const int quad = lane >> 4;
  const int l16 = lane & 15;

  __shared__ __align__(16) bf16 Ks[2][64][72];
  __shared__ __align__(16) bf16 Vt[2][64][72];  // Vt[d][j] = V[j][d]
  __shared__ __align__(16) bf16 Ps[128][68];    // P [query][key]

  const bf16* Qb_ = Q + (size_t)bh * S_ * DH_;
  const bf16* Kb_ = K + (size_t)bh * S_ * DH_;
  const bf16* Vb_ = V + (size_t)bh * S_ * DH_;

  // Q as B-operand frag: queries qb + wv*16 + l16
  short8 bq0, bq1;
  {
    const bf16* qrow = Qb_ + (size_t)(qb + wv * 16 + l16) * DH_ + quad * 8;
    bq0 = *(const short8*)(qrow);
    bq1 = *(const short8*)(qrow + 32);
  }

  float m_r = -1e30f, l_r = 0.f;
  floatx4 o[4];
#pragma unroll
  for (int fd = 0; fd < 4; fd++) o[fd] = {0.f, 0.f, 0.f, 0.f};

  // staging (512 threads): K chunk = 1 x 16B; V = 1 uint4 -> 8 b16 scatters
  const int kr = tid >> 3, ko = (tid & 7) * 8;
  const int vj = tid & 63, vd = (tid >> 6) * 8;

  // prologue: prefetch tile 0 into registers
  uint4 kreg = *(const uint4*)(Kb_ + (size_t)kr * DH_ + ko);
  uint4 vreg = *(const uint4*)(Vb_ + (size_t)vj * DH_ + vd);

  int cur = 0;
  for (int t = 0; t < S_ / 64; t++) {
    // commit prefetched tile into buf[cur]
    *(uint4*)&Ks[cur][kr][ko] = kreg;
    {
      bf16 tmp[8];
      *(uint4*)tmp = vreg;
#pragma unroll
      for (int e = 0; e < 8; e++) Vt[cur][vd + e][vj] = tmp[e];
    }
    __syncthreads();

    // prefetch tile t+1 (clamped; redundant reload on last iter)
    {
      const int tn = (t + 1 < S_ / 64) ? t + 1 : t;
      kreg = *(const uint4*)(Kb_ + (size_t)(tn * 64 + kr) * DH_ + ko);
      vreg = *(const uint4*)(Vb_ + (size_t)(tn * 64 + vj) * DH_ + vd);
    }

    // S^T = K Q^T : lane holds keys fk*16 + quad*4 + r for query wv*16+l16
    float st[4][4];
#pragma unroll
    for (int fk = 0; fk < 4; fk++) {
      short8 ak0 = *(const short8*)&Ks[cur][fk * 16 + l16][quad * 8];
      short8 ak1 = *(const short8*)&Ks[cur][fk * 16 + l16][32 + quad * 8];
      floatx4 acc = {0.f, 0.f, 0.f, 0.f};
      acc = __builtin_amdgcn_mfma_f32_16x16x32_bf16(ak0, bq0, acc, 0, 0, 0);
      acc = __builtin_amdgcn_mfma_f32_16x16x32_bf16(ak1, bq1, acc, 0, 0, 0);
#pragma unroll
      for (int r = 0; r < 4; r++) st[fk][r] = acc[r] * sc2;
    }

    // online softmax per query (in-lane over 16 keys, then xor16/32)
    float mx = st[0][0];
#pragma unroll
    for (int fk = 0; fk < 4; fk++)
#pragma unroll
      for (int r = 0; r < 4; r++) mx = fmaxf(mx, st[fk][r]);
    mx = fmaxf(mx, __shfl_xor(mx, 16));
    mx = fmaxf(mx, __shfl_xor(mx, 32));
    const float mn = fmaxf(m_r, mx);
    const float alpha = exp2f(m_r - mn);
    m_r = mn;
    float rs = 0.f;
#pragma unroll
    for (int fk = 0; fk < 4; fk++) {
      bf16 pk[4];
#pragma unroll
      for (int r = 0; r < 4; r++) {
        const float p = exp2f(st[fk][r] - mn);
        rs += p;
        pk[r] = __float2bfloat16(p);
      }
      *(uint2*)&Ps[wv * 16 + l16][fk * 16 + quad * 4] = *(uint2*)pk;
    }
    rs += __shfl_xor(rs, 16);
    rs += __shfl_xor(rs, 32);
    l_r = alpha * l_r + rs;

    // rescale O: row r of O frag = query quad*4+r; fetch its alpha
#pragma unroll
    for (int r = 0; r < 4; r++) {
      const float a = __shfl(alpha, quad * 20 + r, 64);
#pragma unroll
      for (int fd = 0; fd < 4; fd++) o[fd][r] *= a;
    }

    // O += P V
    short8 ap0 = *(const short8*)&Ps[wv * 16 + l16][quad * 8];
    short8 ap1 = *(const short8*)&Ps[wv * 16 + l16][32 + quad * 8];
#pragma unroll
    for (int fd = 0; fd < 4; fd++) {
      short8 bv0 = *(const short8*)&Vt[cur][fd * 16 + l16][quad * 8];
      short8 bv1 = *(const short8*)&Vt[cur][fd * 16 + l16][32 + quad * 8];
      o[fd] = __builtin_amdgcn_mfma_f32_16x16x32_bf16(ap0, bv0, o[fd], 0, 0, 0);
      o[fd] = __builtin_amdgcn_mfma_f32_16x16x32_bf16(ap1, bv1, o[fd], 0, 0, 0);
    }

    cur ^= 1;
  }

  // epilogue: O row -> query wv*16 + quad*4 + r; its l via shfl
#pragma unroll
  for (int r = 0; r < 4; r++) {
    const float lq = __shfl(l_r, quad * 20 + r, 64);
    const float sc = out_scale / lq;
    const size_t base =
        ((size_t)(b * S_ + qb + wv * 16 + quad * 4 + r)) * D_ + h * DH_;
#pragma unroll
    for (int fd = 0; fd < 4; fd++)
      att[base + fd * 16 + l16] = __float2bfloat16(o[fd][r] * sc);
  }
}

// ---------------------------------------------------------------------------
extern "C" void kernel_launch(void* const* d_in, const int* in_sizes, int n_in,
                              void* d_out, int out_size, void* d_ws, size_t ws_size,
                              hipStream_t stream) {
  const float* x     = (const float*)d_in[0];
  const float* w_qkv = (const float*)d_in[1];
  const float* w_o   = (const float*)d_in[2];
  const float* w1    = (const float*)d_in[3];
  const float* b1    = (const float*)d_in[4];
  const float* w2    = (const float*)d_in[5];
  const float* b2    = (const float*)d_in[6];
  const float* ln1w  = (const float*)d_in[7];
  const float* ln1b  = (const float*)d_in[8];
  const float* ln2w  = (const float*)d_in[9];
  const float* ln2b  = (const float*)d_in[10];
  float* out = (float*)d_out;
  bf16* ws  = (bf16*)d_ws;

  // workspace layout (bf16 elements), with reuse (peak 29,360,128 els = 58.7 MB)
  bf16* h1       = ws;                 // LN1 out; dead after QKV gemm
  bf16* Qb       = ws + 4194304;
  bf16* Kb       = ws + 8388608;
  bf16* Vb       = ws + 12582912;      // Q/K/V dead after flash
  bf16* qkv      = ws + 16777216;      // dead after extract
  bf16* att      = ws;                 // = h1 region
  bf16* attn_out = ws + 16777216;      // dead after LN2
  bf16* x2       = ws + 20971520;
  bf16* h2       = ws + 25165824;
  bf16* g        = ws;                 // h1+Q/K/V regions (dead)
  bf16* wqb      = ws + 4194304;       // overwritten by extract (ok)
  bf16* wob      = ws + 4194304;       // Q region, dead after flash
  bf16* w1b      = ws + 16777216;      // attn_out region, dead
  bf16* w2b      = ws + 16777216;      // w1b dead after FFN1

  const float MM_SCALE   = (float)pow((double)S_ * S_ * DH_, -1.0 / 6.0);
  const float SM_SCALE   = (float)((double)S_ / sqrt(1.31 * 1.65));
  const float GELU_SCALE = (float)pow(0.588 * 0.675, -0.5);
  const float SQRT_TAU   = (float)sqrt(0.2);
  const float SQRT_1MT   = (float)sqrt(0.8);
  const float LOG2E      = 1.4426950408889634f;
  const float qkv_scale  = (float)pow((double)D_ * D3_, -0.25);
  const float o_scale    = (float)pow((double)D_ * D_, -0.25);
  const float w1_scale   = (float)pow((double)D_ * DF_, -0.25);
  const float w2_scale   = (float)pow((double)DF_ * D_, -0.25);

  // 1. LN1
  resid_ln_kernel<false, float, float><<<BS_, 256, 0, stream>>>(
      x, nullptr, ln1w, ln1b, nullptr, h1, 0.f, 0.f);
  // 2. convert w_qkv; QKV gemm (768 blocks)
  cvt_f32_bf16<<<(D3_ * D_ / 4 + 255) / 256, 256, 0, stream>>>(w_qkv, wqb, D3_ * D_ / 4);
  gemm_mfma<0, 128, 128, bf16><<<dim3(D3_ / 128, BS_ / 128), 256, 0, stream>>>(
      h1, wqb, qkv, BS_, D3_, D_, qkv_scale, nullptr, nullptr, 0.f, 0.f);
  // 3. de-interleave
  extract_qkv<<<(3 * BS_ * D_) / 256, 256, 0, stream>>>(qkv, Qb);
  // 4. MFMA flash attention (512 blocks x 8 waves), scores in log2 domain
  flash_attn_mfma<<<dim3(S_ / 128, H_, B_), 512, 0, stream>>>(
      Qb, Kb, Vb, att, MM_SCALE * LOG2E, SM_SCALE * MM_SCALE);
  // 5. convert w_o; out-proj (BM=64 -> 512 blocks)
  cvt_f32_bf16<<<(D_ * D_ / 4 + 255) / 256, 256, 0, stream>>>(w_o, wob, D_ * D_ / 4);
  gemm_mfma<0, 64, 128, bf16><<<dim3(D_ / 128, BS_ / 64), 256, 0, stream>>>(
      att, wob, attn_out, BS_, D_, D_, o_scale, nullptr, nullptr, 0.f, 0.f);
  // 6. residual + LN2
  resid_ln_kernel<true, bf16, float><<<BS_, 256, 0, stream>>>(
      attn_out, x, ln2w, ln2b, x2, h2, SQRT_TAU, SQRT_1MT);
  // 7. convert w1; FFN1 + GELU (1024 blocks)
  cvt_f32_bf16<<<(DF_ * D_ / 4 + 255) / 256, 256, 0, stream>>>(w1, w1b, DF_ * D_ / 4);
  gemm_mfma<1, 128, 128, bf16><<<dim3(DF_ / 128, BS_ / 128), 256, 0, stream>>>(
      h2, w1b, g, BS_, DF_, D_, w1_scale, b1, nullptr, GELU_SCALE, 0.f);
  // 8. convert w2; FFN2 + bias + final residual -> d_out (BM=64 -> 512 blocks)
  cvt_f32_bf16<<<(D_ * DF_ / 4 + 255) / 256, 256, 0, stream>>>(w2, w2b, D_ * DF_ / 4);
  gemm_mfma<2, 64, 128, float><<<dim3(D_ / 128, BS_ / 64), 256, 0, stream>>>(
      g, w2b, out, BS_, D_, DF_, w2_scale, b2, x2, SQRT_TAU, SQRT_1MT);
}

// Round 11
// 421.944 us; speedup vs baseline: 1.2309x; 1.0992x over previous
//
#include <hip/hip_runtime.h>
#include <hip/hip_bf16.h>
#include <math.h>

typedef __hip_bfloat16 bf16;
typedef __attribute__((ext_vector_type(8))) short short8;
typedef __attribute__((ext_vector_type(4))) float floatx4;

#define B_   2
#define S_   2048
#define D_   1024
#define H_   16
#define DH_  64
#define BS_  4096   // B_*S_
#define D3_  3072   // 3*D_
#define DF_  4096   // 4*D_

__device__ __forceinline__ float tof(float v) { return v; }
__device__ __forceinline__ float tof(bf16 v) { return __bfloat162float(v); }
__device__ __forceinline__ void stf(float* p, size_t i, float v) { p[i] = v; }
__device__ __forceinline__ void stf(bf16* p, size_t i, float v) { p[i] = __float2bfloat16(v); }

// async global->LDS 16B copy: lane's data lands at readfirstlane(lds)+lane*16
__device__ __forceinline__ void gload_lds16(const bf16* g, bf16* l) {
  __builtin_amdgcn_global_load_lds(
      (const __attribute__((address_space(1))) unsigned int*)g,
      (__attribute__((address_space(3))) unsigned int*)l, 16, 0, 0);
}

// ---------------------------------------------------------------------------
// fp32 -> bf16 weight conversion (vectorized x4)
// ---------------------------------------------------------------------------
__global__ __launch_bounds__(256) void cvt_f32_bf16(
    const float* __restrict__ in, bf16* __restrict__ out, int n4) {
  int i = blockIdx.x * 256 + threadIdx.x;
  if (i >= n4) return;
  float4 v = ((const float4*)in)[i];
  bf16 o[4] = {__float2bfloat16(v.x), __float2bfloat16(v.y),
               __float2bfloat16(v.z), __float2bfloat16(v.w)};
  ((ulong1*)out)[i] = *(ulong1*)o;
}

// ---------------------------------------------------------------------------
// Fused convert: w_qkv fp32->bf16 with ROW PERMUTE n=d*48+z*16+h -> n2=
// z*1024+h*64+d (so QKV gemm emits [b,s][z,h,d] and no extract pass is
// needed), plus plain convert of w_o. 4 els/thread, both sides coalesced.
// ---------------------------------------------------------------------------
__global__ __launch_bounds__(256) void cvt_qkv_o(
    const float* __restrict__ wqkv, const float* __restrict__ wo,
    bf16* __restrict__ wqb, bf16* __restrict__ wob) {
  const int g = blockIdx.x * 256 + threadIdx.x;  // 4-el group
  if (g < 786432) {                              // 3072*1024/4 : permute+cvt
    const int n2 = g >> 8;                       // dest row (z,h,d)
    const int col = (g & 255) * 4;
    const int z = n2 >> 10, hh = (n2 >> 6) & 15, d = n2 & 63;
    const int n = d * 48 + z * 16 + hh;          // src row
    float4 v = *(const float4*)(wqkv + (size_t)n * 1024 + col);
    bf16 o[4] = {__float2bfloat16(v.x), __float2bfloat16(v.y),
                 __float2bfloat16(v.z), __float2bfloat16(v.w)};
    *(unsigned long long*)(wqb + (size_t)n2 * 1024 + col) =
        *(unsigned long long*)o;
  } else {
    const int g2 = g - 786432;                   // w_o: 1024*1024/4 groups
    float4 v = ((const float4*)wo)[g2];
    bf16 o[4] = {__float2bfloat16(v.x), __float2bfloat16(v.y),
                 __float2bfloat16(v.z), __float2bfloat16(v.w)};
    ((unsigned long long*)wob)[g2] = *(unsigned long long*)o;
  }
}

// ---------------------------------------------------------------------------
// LayerNorm (optionally fused with residual add): one block per row of D_=1024
// ---------------------------------------------------------------------------
template <bool FUSE, typename TA, typename TS>
__global__ __launch_bounds__(256) void resid_ln_kernel(
    const TA* __restrict__ a, const TS* __restrict__ skip,
    const float* __restrict__ w, const float* __restrict__ bias,
    bf16* __restrict__ x2, bf16* __restrict__ hout, float st, float s1t) {
  const int row = blockIdx.x;
  const int tid = threadIdx.x;
  const int base = tid * 4;
  const size_t roff = (size_t)row * D_;

  float xv[4];
#pragma unroll
  for (int i = 0; i < 4; i++) {
    float v = tof(a[roff + base + i]);
    if (FUSE) v = st * v + s1t * tof(skip[roff + base + i]);
    xv[i] = v;
  }
  if (FUSE) {
#pragma unroll
    for (int i = 0; i < 4; i++) x2[roff + base + i] = __float2bfloat16(xv[i]);
  }

  float ls = 0.f, lq = 0.f;
#pragma unroll
  for (int i = 0; i < 4; i++) { ls += xv[i]; lq += xv[i] * xv[i]; }

  __shared__ float ssum[256];
  __shared__ float ssq[256];
  ssum[tid] = ls; ssq[tid] = lq;
  __syncthreads();
  for (int off = 128; off > 0; off >>= 1) {
    if (tid < off) { ssum[tid] += ssum[tid + off]; ssq[tid] += ssq[tid + off]; }
    __syncthreads();
  }
  const float mean = ssum[0] * (1.0f / D_);
  const float var  = ssq[0] * (1.0f / D_) - mean * mean;
  const float rstd = rsqrtf(var + 1e-5f);

#pragma unroll
  for (int i = 0; i < 4; i++) {
    float v = (xv[i] - mean) * rstd * w[base + i] + bias[base + i];
    hout[roff + base + i] = __float2bfloat16(v);
  }
}

// ---------------------------------------------------------------------------
// MFMA GEMM: C[M,N] = epilogue( A[M,K] @ Bw[N,K]^T ), both bf16.
// BM x BN tile, BK=64, 4 waves 2x2.
// ---------------------------------------------------------------------------
template <int EPI, int BM, int BN, typename TC>
__global__ __launch_bounds__(256) void gemm_mfma(
    const bf16* __restrict__ A, const bf16* __restrict__ Bw,
    TC* __restrict__ C, int M, int N, int K, float scale,
    const float* __restrict__ bias, const bf16* __restrict__ resid,
    float st, float s1t) {
  constexpr int FI = BM / 32;
  constexpr int FJ = BN / 32;
  constexpr int NA = BM * 8 / 256;
  constexpr int NB = BN * 8 / 256;

  __shared__ __align__(16) bf16 As[BM][64];
  __shared__ __align__(16) bf16 Bs[BN][64];

  const int tid = threadIdx.x;
  const int lane = tid & 63;
  const int w = tid >> 6;
  const int wm = (w >> 1) * (BM / 2);
  const int wn = (w & 1) * (BN / 2);
  const int quad = lane >> 4;
  const int l16 = lane & 15;
  const int bm = blockIdx.y * BM, bn = blockIdx.x * BN;

  floatx4 acc[FI][FJ];
#pragma unroll
  for (int i = 0; i < FI; i++)
#pragma unroll
    for (int j = 0; j < FJ; j++) acc[i][j] = {0.f, 0.f, 0.f, 0.f};

  const bf16* Ap[NA];
  bf16* lA[NA];
#pragma unroll
  for (int i = 0; i < NA; i++) {
    const int c = tid + i * 256;
    Ap[i] = A + (size_t)(bm + (c >> 3)) * K + (c & 7) * 8;
    lA[i] = (bf16*)As + (size_t)c * 8;
  }
  const bf16* Bp[NB];
  bf16* lB[NB];
#pragma unroll
  for (int i = 0; i < NB; i++) {
    const int c = tid + i * 256;
    Bp[i] = Bw + (size_t)(bn + (c >> 3)) * K + (c & 7) * 8;
    lB[i] = (bf16*)Bs + (size_t)c * 8;
  }

  for (int k0 = 0; k0 < K; k0 += 64) {
    __syncthreads();
#pragma unroll
    for (int i = 0; i < NA; i++) gload_lds16(Ap[i] + k0, lA[i]);
#pragma unroll
    for (int i = 0; i < NB; i++) gload_lds16(Bp[i] + k0, lB[i]);
    __syncthreads();

#pragma unroll
    for (int kc = 0; kc < 2; kc++) {
      short8 af[FI], bf[FJ];
#pragma unroll
      for (int f = 0; f < FI; f++)
        af[f] = *(const short8*)&As[wm + f * 16 + l16][kc * 32 + quad * 8];
#pragma unroll
      for (int f = 0; f < FJ; f++)
        bf[f] = *(const short8*)&Bs[wn + f * 16 + l16][kc * 32 + quad * 8];
#pragma unroll
      for (int fi = 0; fi < FI; fi++)
#pragma unroll
        for (int fj = 0; fj < FJ; fj++)
          acc[fi][fj] = __builtin_amdgcn_mfma_f32_16x16x32_bf16(
              af[fi], bf[fj], acc[fi][fj], 0, 0, 0);
    }
  }

#pragma unroll
  for (int fi = 0; fi < FI; fi++) {
#pragma unroll
    for (int fj = 0; fj < FJ; fj++) {
      const int col = bn + wn + fj * 16 + l16;
#pragma unroll
      for (int r = 0; r < 4; r++) {
        const int row = bm + wm + fi * 16 + quad * 4 + r;
        float v = acc[fi][fj][r];
        if (EPI == 0) {
          v *= scale;
        } else if (EPI == 1) {
          v = (v + bias[col]) * scale;
          v = 0.5f * v * (1.0f + erff(v * 0.70710678118654752f)) * st;
        } else {
          v = (v + bias[col]) * scale;
          v = st * v + s1t * __bfloat162float(resid[(size_t)row * N + col]);
        }
        stf(C, (size_t)row * N + col, v);
      }
    }
  }
}

// ---------------------------------------------------------------------------
// MFMA flash attention, S^T scheme, 512 threads = 8 waves, QT=128, KT=64.
// Reads Q/K/V DIRECTLY from the head-major qkv buffer [b,s][z,h,d]:
// base = qkv + b*S*D3 + h*64 + z*1024, row stride D3 (=3072).
// Double-buffered K/V LDS + register prefetch (one barrier per iter).
// ---------------------------------------------------------------------------
__global__ __launch_bounds__(512) void flash_attn_mfma(
    const bf16* __restrict__ qkv, bf16* __restrict__ att,
    float sc2, float out_scale) {
  const int qb = blockIdx.x * 128;
  const int h = blockIdx.y, b = blockIdx.z;
  const int tid = threadIdx.x;
  const int lane = tid & 63;
  const int wv = tid >> 6;           // 0..7
  const int quad = lane >> 4;
  const int l16 = lane & 15;

  __shared__ __align__(16) bf16 Ks[2][64][72];
  __shared__ __align__(16) bf16 Vt[2][64][72];  // Vt[d][j] = V[j][d]
  __shared__ __align__(16) bf16 Ps[128][68];    // P [query][key]

  const bf16* Qb_ = qkv + (size_t)b * S_ * D3_ + h * DH_;
  const bf16* Kb_ = Qb_ + 1024;
  const bf16* Vb_ = Qb_ + 2048;

  // Q as B-operand frag: queries qb + wv*16 + l16
  short8 bq0, bq1;
  {
    const bf16* qrow = Qb_ + (size_t)(qb + wv * 16 + l16) * D3_ + quad * 8;
    bq0 = *(const short8*)(qrow);
    bq1 = *(const short8*)(qrow + 32);
  }

  float m_r = -1e30f, l_r = 0.f;
  floatx4 o[4];
#pragma unroll
  for (int fd = 0; fd < 4; fd++) o[fd] = {0.f, 0.f, 0.f, 0.f};

  // staging (512 threads): K chunk = 1 x 16B; V = 1 uint4 -> 8 b16 scatters
  const int kr = tid >> 3, ko = (tid & 7) * 8;
  const int vj = tid & 63, vd = (tid >> 6) * 8;

  // prologue: prefetch tile 0 into registers
  uint4 kreg = *(const uint4*)(Kb_ + (size_t)kr * D3_ + ko);
  uint4 vreg = *(const uint4*)(Vb_ + (size_t)vj * D3_ + vd);

  int cur = 0;
  for (int t = 0; t < S_ / 64; t++) {
    // commit prefetched tile into buf[cur]
    *(uint4*)&Ks[cur][kr][ko] = kreg;
    {
      bf16 tmp[8];
      *(uint4*)tmp = vreg;
#pragma unroll
      for (int e = 0; e < 8; e++) Vt[cur][vd + e][vj] = tmp[e];
    }
    __syncthreads();

    // prefetch tile t+1 (clamped; redundant reload on last iter)
    {
      const int tn = (t + 1 < S_ / 64) ? t + 1 : t;
      kreg = *(const uint4*)(Kb_ + (size_t)(tn * 64 + kr) * D3_ + ko);
      vreg = *(const uint4*)(Vb_ + (size_t)(tn * 64 + vj) * D3_ + vd);
    }

    // S^T = K Q^T : lane holds keys fk*16 + quad*4 + r for query wv*16+l16
    float st[4][4];
#pragma unroll
    for (int fk = 0; fk < 4; fk++) {
      short8 ak0 = *(const short8*)&Ks[cur][fk * 16 + l16][quad * 8];
      short8 ak1 = *(const short8*)&Ks[cur][fk * 16 + l16][32 + quad * 8];
      floatx4 acc = {0.f, 0.f, 0.f, 0.f};
      acc = __builtin_amdgcn_mfma_f32_16x16x32_bf16(ak0, bq0, acc, 0, 0, 0);
      acc = __builtin_amdgcn_mfma_f32_16x16x32_bf16(ak1, bq1, acc, 0, 0, 0);
#pragma unroll
      for (int r = 0; r < 4; r++) st[fk][r] = acc[r] * sc2;
    }

    // online softmax per query (in-lane over 16 keys, then xor16/32)
    float mx = st[0][0];
#pragma unroll
    for (int fk = 0; fk < 4; fk++)
#pragma unroll
      for (int r = 0; r < 4; r++) mx = fmaxf(mx, st[fk][r]);
    mx = fmaxf(mx, __shfl_xor(mx, 16));
    mx = fmaxf(mx, __shfl_xor(mx, 32));
    const float mn = fmaxf(m_r, mx);
    const float alpha = exp2f(m_r - mn);
    m_r = mn;
    float rs = 0.f;
#pragma unroll
    for (int fk = 0; fk < 4; fk++) {
      bf16 pk[4];
#pragma unroll
      for (int r = 0; r < 4; r++) {
        const float p = exp2f(st[fk][r] - mn);
        rs += p;
        pk[r] = __float2bfloat16(p);
      }
      *(uint2*)&Ps[wv * 16 + l16][fk * 16 + quad * 4] = *(uint2*)pk;
    }
    rs += __shfl_xor(rs, 16);
    rs += __shfl_xor(rs, 32);
    l_r = alpha * l_r + rs;

    // rescale O: row r of O frag = query quad*4+r; fetch its alpha
#pragma unroll
    for (int r = 0; r < 4; r++) {
      const float a = __shfl(alpha, quad * 20 + r, 64);
#pragma unroll
      for (int fd = 0; fd < 4; fd++) o[fd][r] *= a;
    }

    // O += P V
    short8 ap0 = *(const short8*)&Ps[wv * 16 + l16][quad * 8];
    short8 ap1 = *(const short8*)&Ps[wv * 16 + l16][32 + quad * 8];
#pragma unroll
    for (int fd = 0; fd < 4; fd++) {
      short8 bv0 = *(const short8*)&Vt[cur][fd * 16 + l16][quad * 8];
      short8 bv1 = *(const short8*)&Vt[cur][fd * 16 + l16][32 + quad * 8];
      o[fd] = __builtin_amdgcn_mfma_f32_16x16x32_bf16(ap0, bv0, o[fd], 0, 0, 0);
      o[fd] = __builtin_amdgcn_mfma_f32_16x16x32_bf16(ap1, bv1, o[fd], 0, 0, 0);
    }

    cur ^= 1;
  }

  // epilogue: O row -> query wv*16 + quad*4 + r; its l via shfl
#pragma unroll
  for (int r = 0; r < 4; r++) {
    const float lq = __shfl(l_r, quad * 20 + r, 64);
    const float sc = out_scale / lq;
    const size_t base =
        ((size_t)(b * S_ + qb + wv * 16 + quad * 4 + r)) * D_ + h * DH_;
#pragma unroll
    for (int fd = 0; fd < 4; fd++)
      att[base + fd * 16 + l16] = __float2bfloat16(o[fd][r] * sc);
  }
}

// ---------------------------------------------------------------------------
extern "C" void kernel_launch(void* const* d_in, const int* in_sizes, int n_in,
                              void* d_out, int out_size, void* d_ws, size_t ws_size,
                              hipStream_t stream) {
  const float* x     = (const float*)d_in[0];
  const float* w_qkv = (const float*)d_in[1];
  const float* w_o   = (const float*)d_in[2];
  const float* w1    = (const float*)d_in[3];
  const float* b1    = (const float*)d_in[4];
  const float* w2    = (const float*)d_in[5];
  const float* b2    = (const float*)d_in[6];
  const float* ln1w  = (const float*)d_in[7];
  const float* ln1b  = (const float*)d_in[8];
  const float* ln2w  = (const float*)d_in[9];
  const float* ln2b  = (const float*)d_in[10];
  float* out = (float*)d_out;
  bf16* ws  = (bf16*)d_ws;

  // workspace layout (bf16 els), liveness-audited, peak 29,360,128 els (58.7MB)
  // slots: 1 cvt_qo, 2 LN1, 3 QKVgemm, 4 flash, 5 Oproj, 6 LN2,
  //        6.5 cvt w1, 7 FFN1, 7.5 cvt w2, 8 FFN2
  bf16* h1       = ws;                 // [0,4.19M)      live 2->3
  bf16* att      = ws;                 //                live 4->5 (h1 dead)
  bf16* h2       = ws + 20971520;      // [20.97,25.17M) live 6->7
  bf16* wqb      = ws + 4194304;       // [4.19,7.34M)   live 1->3
  bf16* wob      = ws + 7340032;       // [7.34,8.39M)   live 1->5
  bf16* attn_out = ws + 8388608;       // [8.39,12.58M)  live 5->6
  bf16* qkv      = ws + 16777216;      // [16.78,29.36M) live 3->4
  bf16* w1b      = ws + 16777216;      // [16.78,20.97M) live 6.5->7 (qkv dead)
  bf16* w2b      = ws + 16777216;      // [16.78,20.97M) live 7.5->8 (w1b dead)
  bf16* x2       = ws + 25165824;      // [25.17,29.36M) live 6->8
  bf16* g        = ws;                 // [0,16.78M)     live 7->8 (all dead)

  const float MM_SCALE   = (float)pow((double)S_ * S_ * DH_, -1.0 / 6.0);
  const float SM_SCALE   = (float)((double)S_ / sqrt(1.31 * 1.65));
  const float GELU_SCALE = (float)pow(0.588 * 0.675, -0.5);
  const float SQRT_TAU   = (float)sqrt(0.2);
  const float SQRT_1MT   = (float)sqrt(0.8);
  const float LOG2E      = 1.4426950408889634f;
  const float qkv_scale  = (float)pow((double)D_ * D3_, -0.25);
  const float o_scale    = (float)pow((double)D_ * D_, -0.25);
  const float w1_scale   = (float)pow((double)D_ * DF_, -0.25);
  const float w2_scale   = (float)pow((double)DF_ * D_, -0.25);

  // 1. convert w_qkv (permuted) + w_o
  cvt_qkv_o<<<4096, 256, 0, stream>>>(w_qkv, w_o, wqb, wob);
  // 2. LN1
  resid_ln_kernel<false, float, float><<<BS_, 256, 0, stream>>>(
      x, nullptr, ln1w, ln1b, nullptr, h1, 0.f, 0.f);
  // 3. QKV gemm -> head-major qkv (768 blocks)
  gemm_mfma<0, 128, 128, bf16><<<dim3(D3_ / 128, BS_ / 128), 256, 0, stream>>>(
      h1, wqb, qkv, BS_, D3_, D_, qkv_scale, nullptr, nullptr, 0.f, 0.f);
  // 4. MFMA flash attention (512 blocks x 8 waves), reads qkv directly
  flash_attn_mfma<<<dim3(S_ / 128, H_, B_), 512, 0, stream>>>(
      qkv, att, MM_SCALE * LOG2E, SM_SCALE * MM_SCALE);
  // 5. out-proj (BM=64 -> 512 blocks)
  gemm_mfma<0, 64, 128, bf16><<<dim3(D_ / 128, BS_ / 64), 256, 0, stream>>>(
      att, wob, attn_out, BS_, D_, D_, o_scale, nullptr, nullptr, 0.f, 0.f);
  // 6. residual + LN2
  resid_ln_kernel<true, bf16, float><<<BS_, 256, 0, stream>>>(
      attn_out, x, ln2w, ln2b, x2, h2, SQRT_TAU, SQRT_1MT);
  // 6.5 convert w1; 7. FFN1 + GELU (1024 blocks)
  cvt_f32_bf16<<<(DF_ * D_ / 4 + 255) / 256, 256, 0, stream>>>(w1, w1b, DF_ * D_ / 4);
  gemm_mfma<1, 128, 128, bf16><<<dim3(DF_ / 128, BS_ / 128), 256, 0, stream>>>(
      h2, w1b, g, BS_, DF_, D_, w1_scale, b1, nullptr, GELU_SCALE, 0.f);
  // 7.5 convert w2; 8. FFN2 + bias + final residual -> d_out (512 blocks)
  cvt_f32_bf16<<<(D_ * DF_ / 4 + 255) / 256, 256, 0, stream>>>(w2, w2b, D_ * DF_ / 4);
  gemm_mfma<2, 64, 128, float><<<dim3(D_ / 128, BS_ / 64), 256, 0, stream>>>(
      g, w2b, out, BS_, D_, DF_, w2_scale, b2, x2, SQRT_TAU, SQRT_1MT);
}